// Round 8
// baseline (326.508 us; speedup 1.0000x reference)
//
#include <hip/hip_runtime.h>
#include <hip/hip_bf16.h>
#include <stdint.h>

// Problem constants
#define NS   8
#define NB   2
#define CK   64
#define CV   64
#define HWN  4096
#define SHW  32768
#define RADIUS_ 0.1f
#define MASK_W  6.103515625e-6f   // 0.2 / 8 / 64 / 64

// Tiling
#define TM    32
#define NW    8
#define QS_STR 68           // fp32 Q stage stride
#define P_STR  40           // bf16 P row stride (80 B, 16B-aligned)
#define SBIAS 24.0f
#define KS    4             // key splits (v2)

// Workspace layout
#define KT_ELEMS (NS * NB * CK * HWN)       // 4,194,304
#define KT_BYTES ((size_t)KT_ELEMS * 2)     // 8 MB fp16 transposed K
#define VB_BYTES ((size_t)KT_ELEMS * 2)     // 8 MB bf16 V
#define MASK_OFF (KT_BYTES + VB_BYTES)
#define WS_NEED  (MASK_OFF + (size_t)NB * CV * 4)            // round-6 path
#define ONUM_OFF (MASK_OFF + 4096)
#define ONUM_BYTES ((size_t)KS * NB * HWN * CV * 4)          // 8.4 MB
#define ODEN_OFF (ONUM_OFF + ONUM_BYTES)
#define ODEN_BYTES ((size_t)KS * NB * HWN * 4)               // 128 KB
#define WS2      (ODEN_OFF + ODEN_BYTES)                     // ~25.4 MB

typedef __bf16    bf16x8 __attribute__((ext_vector_type(8)));
typedef _Float16  f16x8  __attribute__((ext_vector_type(8)));
typedef float     f32x4  __attribute__((ext_vector_type(4)));
typedef unsigned short u16x8 __attribute__((ext_vector_type(8)));

__device__ __forceinline__ unsigned short f2bfu(float x) {
  __hip_bfloat16 h = __float2bfloat16(x);
  return __builtin_bit_cast(unsigned short, h);
}
__device__ __forceinline__ bf16x8 ld_bf8_lds(const unsigned short* p) {
  u16x8 u = *(const u16x8*)p;
  return __builtin_bit_cast(bf16x8, u);
}

// ---------------------------------------------------------------------------
// Round-6 mask kernel (fallback path)
// ---------------------------------------------------------------------------
__global__ __launch_bounds__(256) void maskpv_kernel(
    const float* __restrict__ vals, const float* __restrict__ disp,
    const int* __restrict__ seq, float* __restrict__ maskadd)
{
  const int b = blockIdx.x >> 6;
  const int v = blockIdx.x & 63;
  const int t = threadIdx.x;

  float dist[NS];
  #pragma unroll
  for (int s = 0; s < NS; ++s) {
    float i0 = (float)seq[(b * NS + s) * 2 + 0];
    float i1 = (float)seq[(b * NS + s) * 2 + 1];
    dist[s] = sqrtf((i1 - 5.f) * (i1 - 5.f) + (i0 - 5.f) * (i0 - 5.f));
  }
  float acc = 0.f;
  for (int hw = t; hw < HWN; hw += 256) {
    float dp = disp[b * HWN + hw];
    #pragma unroll
    for (int s = 0; s < NS; ++s)
      if (fabsf(dist[s] * dp) > RADIUS_)
        acc += vals[((size_t)((s * NB + b) * CV + v)) * HWN + hw];
  }
  #pragma unroll
  for (int m = 32; m >= 1; m >>= 1) acc += __shfl_xor(acc, m);
  __shared__ float red[4];
  if ((t & 63) == 0) red[t >> 6] = acc;
  __syncthreads();
  if (t == 0) maskadd[b * CV + v] = MASK_W * (red[0] + red[1] + red[2] + red[3]);
}

// ---------------------------------------------------------------------------
// Pre-pass: K fp32 [S,B,CK,HW] -> fp16 transposed kT[b][key = s*HW+hw][c]
// ---------------------------------------------------------------------------
#define PK_STR 72
__global__ __launch_bounds__(512) void prep_k(
    const float* __restrict__ keys, _Float16* __restrict__ kT)
{
  __shared__ _Float16 lds[256 * PK_STR];
  const int t     = threadIdx.x;
  const int blk   = blockIdx.x;
  const int chunk = blk & 15;
  const int s     = (blk >> 4) & 7;
  const int b     = blk >> 7;
  const int hw0   = chunk * 256;
  const int c_st  = t >> 3;
  const int msub  = (t & 7) * 8;

  const float* krow = keys + ((size_t)((s * NB + b) * CK + c_st)) * HWN + hw0;
  #pragma unroll
  for (int r = 0; r < 4; ++r) {
    const int m0 = msub + r * 64;
    f32x4 k0 = *(const f32x4*)(krow + m0);
    f32x4 k1 = *(const f32x4*)(krow + m0 + 4);
    #pragma unroll
    for (int j = 0; j < 4; ++j) {
      lds[(m0 + j)     * PK_STR + c_st] = (_Float16)k0[j];
      lds[(m0 + 4 + j) * PK_STR + c_st] = (_Float16)k1[j];
    }
  }
  __syncthreads();

  _Float16* kout = kT + ((size_t)(b * SHW + s * HWN + hw0)) * CK;
  const int mm = t >> 3, c0 = (t & 7) * 8;
  #pragma unroll
  for (int r2 = 0; r2 < 4; ++r2) {
    const int m = mm + r2 * 64;
    u16x8 v = *(const u16x8*)&lds[m * PK_STR + c0];
    *(u16x8*)(kout + (size_t)m * CK + c0) = v;
  }
}

// ---------------------------------------------------------------------------
// Pre-pass: V fp32 -> bf16 AND fused mask accumulation (atomicAdd per block).
// Each block covers 2048 consecutive elems = half of one [s,b,c,:] row.
// ---------------------------------------------------------------------------
__global__ __launch_bounds__(256) void prep_vm(
    const float* __restrict__ vals, const float* __restrict__ disp,
    const int* __restrict__ seq, unsigned short* __restrict__ vbf,
    float* __restrict__ maskadd)
{
  const int t  = threadIdx.x;
  const size_t i0 = (size_t)blockIdx.x * 2048;
  const int hw0 = (int)(i0 & 4095);
  const int c   = (int)((i0 >> 12) & 63);
  const int b   = (int)((i0 >> 18) & 1);
  const int s   = (int)(i0 >> 19);

  float j0 = (float)seq[(b * NS + s) * 2 + 0];
  float j1 = (float)seq[(b * NS + s) * 2 + 1];
  const float dist = sqrtf((j1 - 5.f) * (j1 - 5.f) + (j0 - 5.f) * (j0 - 5.f));

  const size_t i = i0 + (size_t)t * 8;
  const int hw = hw0 + t * 8;
  f32x4 a = *(const f32x4*)(vals + i);
  f32x4 bb = *(const f32x4*)(vals + i + 4);
  f32x4 d0 = *(const f32x4*)(disp + (size_t)b * HWN + hw);
  f32x4 d1 = *(const f32x4*)(disp + (size_t)b * HWN + hw + 4);
  u16x8 o;
  float acc = 0.f;
  #pragma unroll
  for (int j = 0; j < 4; ++j) {
    o[j]     = f2bfu(a[j]);
    o[4 + j] = f2bfu(bb[j]);
    if (fabsf(dist * d0[j]) > RADIUS_) acc += a[j];
    if (fabsf(dist * d1[j]) > RADIUS_) acc += bb[j];
  }
  *(u16x8*)(vbf + i) = o;

  #pragma unroll
  for (int m = 32; m >= 1; m >>= 1) acc += __shfl_xor(acc, m);
  __shared__ float red[4];
  if ((t & 63) == 0) red[t >> 6] = acc;
  __syncthreads();
  if (t == 0)
    atomicAdd(&maskadd[b * CV + c],
              MASK_W * (red[0] + red[1] + red[2] + red[3]));
}

// ---------------------------------------------------------------------------
// attn_v2: TM=64 rows/block, key-split KS=4 across blocks.
// XCD-L2 partition: xcd = bidx&7 = (ks<<1)|b -> each XCD's K/V slice = 2 MB,
// resident in its 4 MB private L2 (round-robin dispatch heuristic).
// Waves: rg = w>>2 (row half), kq = w&3 (key quadrant). 64 iters x 128 keys.
// Partials (additive, fixed-bias softmax) -> onum/odenom workspace.
// ---------------------------------------------------------------------------
struct __align__(16) SmemV2 {
  union {
    float qs[64 * QS_STR];                // 17408 B (prologue)
    unsigned short p[NW][2][16 * P_STR];  // 20480 B (main loop)
    struct {
      float obuf[4][32][64];              // 32768 B (epilogue)
      float dbuf[4][32];                  // 512 B
    } epi;
  };
};

__global__ __launch_bounds__(512) void attn_v2(
    const _Float16* __restrict__ kT,        // [B][SHW][CK] fp16
    const unsigned short* __restrict__ vbf, // [S,B,CV,HW] bf16
    const float* __restrict__ query,        // [B,CK,HW] fp32
    float* __restrict__ onum,               // [KS][B][HWN][CV]
    float* __restrict__ odenom)             // [KS][B][HWN]
{
  __shared__ SmemV2 sm;
  const int t    = threadIdx.x;
  const int w    = t >> 6;
  const int lane = t & 63;
  const int quad = lane >> 4;
  const int l15  = lane & 15;
  const int kq   = w & 3;
  const int rg   = w >> 2;
  const int bidx = blockIdx.x;
  // XCD-aware decode: all blocks with equal (b,ks) share bidx&7 -> same XCD.
  const int xcd  = bidx & 7;
  const int b    = xcd & 1;
  const int ks   = xcd >> 1;
  const int tile = bidx >> 3;            // 0..63
  const int n0   = tile * 64;

  // --- Stage Q (64 rows) transposed fp32, then fp16 A-fragments ---
  {
    const int qc   = t >> 3;
    const int noff = (t & 7) * 8;
    const int slot = qc ^ ((t & 7) << 2);
    const float* qp = query + (size_t)(b * CK + qc) * HWN + n0 + noff;
    f32x4 q0 = *(const f32x4*)(qp);
    f32x4 q1 = *(const f32x4*)(qp + 4);
    #pragma unroll
    for (int j = 0; j < 4; ++j) {
      sm.qs[(noff + j)     * QS_STR + slot] = q0[j];
      sm.qs[(noff + 4 + j) * QS_STR + slot] = q1[j];
    }
  }
  __syncthreads();
  f16x8 qf[2][2];
  #pragma unroll
  for (int f = 0; f < 2; ++f) {
    const int n  = rg * 32 + f * 16 + l15;
    const int sw = ((n >> 3) & 7) << 2;
    const float* base = &sm.qs[n * QS_STR];
    #pragma unroll
    for (int h = 0; h < 2; ++h) {
      const int c0 = (h * 32 + quad * 8) ^ sw;
      f32x4 a  = *(const f32x4*)(base + c0);
      f32x4 bb = *(const f32x4*)(base + (c0 ^ 4));
      f16x8 q;
      #pragma unroll
      for (int j = 0; j < 4; ++j) { q[j] = (_Float16)a[j]; q[4 + j] = (_Float16)bb[j]; }
      qf[f][h] = q;
    }
  }
  __syncthreads();  // qs aliases p region

  f32x4 Of[2][4];
  f32x4 Ol[2];
  #pragma unroll
  for (int f = 0; f < 2; ++f) {
    #pragma unroll
    for (int cf = 0; cf < 4; ++cf) Of[f][cf] = (f32x4){0.f, 0.f, 0.f, 0.f};
    Ol[f] = (f32x4){0.f, 0.f, 0.f, 0.f};
  }
  bf16x8 vones;
  #pragma unroll
  for (int i = 0; i < 8; ++i)
    vones[i] = __builtin_bit_cast(__bf16, (unsigned short)0x3F80);

  const _Float16* kb = kT + (size_t)b * SHW * CK;
  const int key_base = ks * (SHW / KS) + kq * 32;

  for (int it = 0; it < (SHW / KS) / 128; ++it) {   // 64 iters
    const int key0 = key_base + it * 128;

    // K B-fragments straight from global (fp16, [key][c] layout)
    f16x8 kf[2][2];
    #pragma unroll
    for (int g = 0; g < 2; ++g)
      #pragma unroll
      for (int h = 0; h < 2; ++h)
        kf[g][h] = *(const f16x8*)(kb +
            (size_t)(key0 + g * 16 + l15) * CK + h * 32 + quad * 8);

    // V B-fragments straight from global (bf16)
    const int sfrm = key0 >> 12;
    const int hwv  = (key0 & 4095) + quad * 8;
    bf16x8 vf[4];
    #pragma unroll
    for (int cf = 0; cf < 4; ++cf)
      vf[cf] = ld_bf8_lds(vbf +
          ((size_t)((sfrm * NB + b) * CV + cf * 16 + l15)) * HWN + hwv);

    // S = Q @ K^T (fp16 MFMA, K=64)
    f32x4 sf[2][2];
    #pragma unroll
    for (int f = 0; f < 2; ++f)
      #pragma unroll
      for (int g = 0; g < 2; ++g) {
        f32x4 acc = (f32x4){0.f, 0.f, 0.f, 0.f};
        acc = __builtin_amdgcn_mfma_f32_16x16x32_f16(qf[f][0], kf[g][0], acc, 0, 0, 0);
        acc = __builtin_amdgcn_mfma_f32_16x16x32_f16(qf[f][1], kf[g][1], acc, 0, 0, 0);
        sf[f][g] = acc;
      }

    // P = exp(S - SBIAS)
    #pragma unroll
    for (int f = 0; f < 2; ++f)
      #pragma unroll
      for (int g = 0; g < 2; ++g)
        #pragma unroll
        for (int r = 0; r < 4; ++r)
          sf[f][g][r] = __expf(sf[f][g][r] - SBIAS);

    // P: C/D -> LDS -> A layout (per-wave, one wait)
    #pragma unroll
    for (int f = 0; f < 2; ++f)
      #pragma unroll
      for (int g = 0; g < 2; ++g)
        #pragma unroll
        for (int r = 0; r < 4; ++r)
          sm.p[w][f][(quad * 4 + r) * P_STR + g * 16 + l15] = f2bfu(sf[f][g][r]);
    asm volatile("s_waitcnt lgkmcnt(0)" ::: "memory");
    bf16x8 pf[2];
    #pragma unroll
    for (int f = 0; f < 2; ++f)
      pf[f] = ld_bf8_lds(&sm.p[w][f][l15 * P_STR + quad * 8]);

    // O += P @ V, l += P @ 1
    #pragma unroll
    for (int f = 0; f < 2; ++f) {
      #pragma unroll
      for (int cf = 0; cf < 4; ++cf)
        Of[f][cf] = __builtin_amdgcn_mfma_f32_16x16x32_bf16(pf[f], vf[cf], Of[f][cf], 0, 0, 0);
      Ol[f] = __builtin_amdgcn_mfma_f32_16x16x32_bf16(pf[f], vones, Ol[f], 0, 0, 0);
    }
  }

  __syncthreads();  // retire p usage before epi alias

  // --- Epilogue: reduce the 4 key-quadrant waves per row-half, store partials ---
  #pragma unroll
  for (int phase = 0; phase < 2; ++phase) {
    if (rg == phase) {
      #pragma unroll
      for (int f = 0; f < 2; ++f)
        #pragma unroll
        for (int r = 0; r < 4; ++r) {
          const int row = f * 16 + quad * 4 + r;
          if (l15 == 0) sm.epi.dbuf[kq][row] = Ol[f][r];
          #pragma unroll
          for (int cf = 0; cf < 4; ++cf)
            sm.epi.obuf[kq][row][cf * 16 + l15] = Of[f][cf][r];
        }
    }
    __syncthreads();
    {
      const int row = t >> 4;          // 0..31
      const int v4  = (t & 15) * 4;
      f32x4 acc = *(const f32x4*)&sm.epi.obuf[0][row][v4];
      #pragma unroll
      for (int q = 1; q < 4; ++q)
        acc += *(const f32x4*)&sm.epi.obuf[q][row][v4];
      *(f32x4*)&onum[((size_t)(ks * NB + b) * HWN + n0 + phase * 32 + row) * CV + v4] = acc;
      if (t < 32) {
        float d = sm.epi.dbuf[0][t] + sm.epi.dbuf[1][t] +
                  sm.epi.dbuf[2][t] + sm.epi.dbuf[3][t];
        odenom[(size_t)(ks * NB + b) * HWN + n0 + phase * 32 + t] = d;
      }
    }
    __syncthreads();
  }
}

// ---------------------------------------------------------------------------
// Finalize: out[b][v][hw] = sum_ks onum / sum_ks odenom + mask  (LDS transpose)
// ---------------------------------------------------------------------------
__global__ __launch_bounds__(256) void finalize_k(
    const float* __restrict__ onum, const float* __restrict__ odenom,
    const float* __restrict__ maskadd, float* __restrict__ out)
{
  __shared__ float tile[64][68];
  __shared__ float dinv[64];
  __shared__ float ml[64];
  const int t   = threadIdx.x;
  const int b   = blockIdx.x >> 6;
  const int hw0 = (blockIdx.x & 63) * 64;

  #pragma unroll
  for (int pass = 0; pass < 4; ++pass) {
    const int row = pass * 16 + (t >> 4);
    const int v4  = (t & 15) * 4;
    f32x4 acc = (f32x4){0.f, 0.f, 0.f, 0.f};
    #pragma unroll
    for (int ks = 0; ks < KS; ++ks)
      acc += *(const f32x4*)&onum[((size_t)(ks * NB + b) * HWN + hw0 + row) * CV + v4];
    *(f32x4*)&tile[row][v4] = acc;
  }
  if (t < 64) {
    float d = 0.f;
    #pragma unroll
    for (int ks = 0; ks < KS; ++ks)
      d += odenom[(size_t)(ks * NB + b) * HWN + hw0 + t];
    dinv[t] = 1.f / fmaxf(d, 1e-30f);
  }
  if (t >= 64 && t < 128) ml[t - 64] = maskadd[b * CV + (t - 64)];
  __syncthreads();

  #pragma unroll
  for (int pass = 0; pass < 4; ++pass) {
    const int v   = pass * 16 + (t >> 4);
    const int hw4 = (t & 15) * 4;
    f32x4 o;
    #pragma unroll
    for (int j = 0; j < 4; ++j)
      o[j] = tile[hw4 + j][v] * dinv[hw4 + j] + ml[v];
    *(f32x4*)&out[((size_t)(b * CV + v)) * HWN + hw0 + hw4] = o;
  }
}

// ---------------------------------------------------------------------------
// Round-6 attention (fallback)
// ---------------------------------------------------------------------------
struct __align__(16) SmemF {
  union {
    float qs[TM * QS_STR];
    unsigned short p[NW][2][16 * P_STR];
    struct {
      float obuf[NW][TM][CV];
      float lbuf[NW][TM];
    } epi;
  };
};

__global__ __launch_bounds__(512) void attn_fast(
    const _Float16* __restrict__ kT, const unsigned short* __restrict__ vbf,
    const float* __restrict__ query, const float* __restrict__ maskadd,
    float* __restrict__ out)
{
  __shared__ SmemF sm;
  const int t    = threadIdx.x;
  const int w    = t >> 6;
  const int lane = t & 63;
  const int quad = lane >> 4;
  const int l15  = lane & 15;
  const int bidx = blockIdx.x;
  const int b    = bidx & 1;
  const int n0   = ((bidx >> 1) & 127) * TM;

  if (t < 256) {
    const int qc   = t >> 2;
    const int noff = (t & 3) * 8;
    const int slot = qc ^ ((t & 3) << 2);
    const float* qp = query + (size_t)(b * CK + qc) * HWN + n0 + noff;
    f32x4 q0 = *(const f32x4*)(qp);
    f32x4 q1 = *(const f32x4*)(qp + 4);
    #pragma unroll
    for (int j = 0; j < 4; ++j) {
      sm.qs[(noff + j)     * QS_STR + slot] = q0[j];
      sm.qs[(noff + 4 + j) * QS_STR + slot] = q1[j];
    }
  }
  __syncthreads();
  f16x8 qf[2][2];
  #pragma unroll
  for (int f = 0; f < 2; ++f) {
    const int n  = f * 16 + l15;
    const int sw = ((n >> 3) & 7) << 2;
    const float* base = &sm.qs[n * QS_STR];
    #pragma unroll
    for (int h = 0; h < 2; ++h) {
      const int c0 = (h * 32 + quad * 8) ^ sw;
      f32x4 a  = *(const f32x4*)(base + c0);
      f32x4 bb = *(const f32x4*)(base + (c0 ^ 4));
      f16x8 q;
      #pragma unroll
      for (int j = 0; j < 4; ++j) { q[j] = (_Float16)a[j]; q[4 + j] = (_Float16)bb[j]; }
      qf[f][h] = q;
    }
  }
  __syncthreads();

  f32x4 Of[2][4];
  f32x4 Ol[2];
  #pragma unroll
  for (int f = 0; f < 2; ++f) {
    #pragma unroll
    for (int cf = 0; cf < 4; ++cf) Of[f][cf] = (f32x4){0.f, 0.f, 0.f, 0.f};
    Ol[f] = (f32x4){0.f, 0.f, 0.f, 0.f};
  }
  bf16x8 vones;
  #pragma unroll
  for (int i = 0; i < 8; ++i)
    vones[i] = __builtin_bit_cast(__bf16, (unsigned short)0x3F80);

  const _Float16* kbase = kT + (size_t)b * SHW * CK;

  for (int it = 0; it < SHW / 256; ++it) {
    const int key0 = it * 256 + w * 32;
    f16x8 kf[2][2];
    #pragma unroll
    for (int g = 0; g < 2; ++g)
      #pragma unroll
      for (int h = 0; h < 2; ++h)
        kf[g][h] = *(const f16x8*)(kbase +
            (size_t)(key0 + g * 16 + l15) * CK + h * 32 + quad * 8);

    const int s   = it >> 4;
    const int hwv = (it & 15) * 256 + w * 32 + quad * 8;
    bf16x8 vf[4];
    #pragma unroll
    for (int cf = 0; cf < 4; ++cf)
      vf[cf] = ld_bf8_lds(vbf +
          ((size_t)((s * NB + b) * CV + cf * 16 + l15)) * HWN + hwv);

    f32x4 sf[2][2];
    #pragma unroll
    for (int f = 0; f < 2; ++f)
      #pragma unroll
      for (int g = 0; g < 2; ++g) {
        f32x4 acc = (f32x4){0.f, 0.f, 0.f, 0.f};
        acc = __builtin_amdgcn_mfma_f32_16x16x32_f16(qf[f][0], kf[g][0], acc, 0, 0, 0);
        acc = __builtin_amdgcn_mfma_f32_16x16x32_f16(qf[f][1], kf[g][1], acc, 0, 0, 0);
        sf[f][g] = acc;
      }

    #pragma unroll
    for (int f = 0; f < 2; ++f)
      #pragma unroll
      for (int g = 0; g < 2; ++g)
        #pragma unroll
        for (int r = 0; r < 4; ++r)
          sf[f][g][r] = __expf(sf[f][g][r] - SBIAS);

    #pragma unroll
    for (int f = 0; f < 2; ++f)
      #pragma unroll
      for (int g = 0; g < 2; ++g)
        #pragma unroll
        for (int r = 0; r < 4; ++r)
          sm.p[w][f][(quad * 4 + r) * P_STR + g * 16 + l15] = f2bfu(sf[f][g][r]);
    asm volatile("s_waitcnt lgkmcnt(0)" ::: "memory");
    bf16x8 pf[2];
    #pragma unroll
    for (int f = 0; f < 2; ++f)
      pf[f] = ld_bf8_lds(&sm.p[w][f][l15 * P_STR + quad * 8]);

    #pragma unroll
    for (int f = 0; f < 2; ++f) {
      #pragma unroll
      for (int cf = 0; cf < 4; ++cf)
        Of[f][cf] = __builtin_amdgcn_mfma_f32_16x16x32_bf16(pf[f], vf[cf], Of[f][cf], 0, 0, 0);
      Ol[f] = __builtin_amdgcn_mfma_f32_16x16x32_bf16(pf[f], vones, Ol[f], 0, 0, 0);
    }
  }

  __syncthreads();
  #pragma unroll
  for (int f = 0; f < 2; ++f)
    #pragma unroll
    for (int r = 0; r < 4; ++r) {
      const int row = f * 16 + quad * 4 + r;
      if (l15 == 0) sm.epi.lbuf[w][row] = Ol[f][r];
      #pragma unroll
      for (int cf = 0; cf < 4; ++cf)
        sm.epi.obuf[w][row][cf * 16 + l15] = Of[f][cf][r];
    }
  __syncthreads();
  {
    const int n   = t & 31;
    const int vhi = t >> 5;
    float denom = 0.f;
    #pragma unroll
    for (int ww = 0; ww < NW; ++ww) denom += sm.epi.lbuf[ww][n];
    const float inv = 1.f / fmaxf(denom, 1e-30f);
    #pragma unroll
    for (int g = 0; g < 4; ++g) {
      const int v = vhi + 16 * g;
      float num = 0.f;
      #pragma unroll
      for (int ww = 0; ww < NW; ++ww) num += sm.epi.obuf[ww][n][v];
      out[((size_t)(b * CV + v)) * HWN + n0 + n] = num * inv + maskadd[b * CV + v];
    }
  }
}

// ---------------------------------------------------------------------------
extern "C" void kernel_launch(void* const* d_in, const int* in_sizes, int n_in,
                              void* d_out, int out_size, void* d_ws, size_t ws_size,
                              hipStream_t stream) {
  const float* keys  = (const float*)d_in[0];
  const float* vals  = (const float*)d_in[1];
  const float* query = (const float*)d_in[2];
  const float* disp  = (const float*)d_in[3];
  const int*   seq   = (const int*)d_in[4];
  float*       out   = (float*)d_out;

  _Float16*       kT   = (_Float16*)d_ws;
  unsigned short* vbf  = (unsigned short*)((char*)d_ws + KT_BYTES);
  float*          mask = (float*)((char*)d_ws + MASK_OFF);

  if (ws_size >= WS2) {
    float* onum   = (float*)((char*)d_ws + ONUM_OFF);
    float* odenom = (float*)((char*)d_ws + ODEN_OFF);
    hipMemsetAsync(mask, 0, (size_t)NB * CV * 4, stream);
    prep_k<<<NB * NS * 16, 512, 0, stream>>>(keys, kT);
    prep_vm<<<KT_ELEMS / 2048, 256, 0, stream>>>(vals, disp, seq, vbf, mask);
    attn_v2<<<NB * 64 * KS, 512, 0, stream>>>(kT, vbf, query, onum, odenom);
    finalize_k<<<NB * (HWN / 64), 256, 0, stream>>>(onum, odenom, mask, out);
  } else {
    prep_k<<<NB * NS * 16, 512, 0, stream>>>(keys, kT);
    maskpv_kernel<<<NB * CV, 256, 0, stream>>>(vals, disp, seq, mask);
    {
      float* dummy = mask;
      prep_vm<<<KT_ELEMS / 2048, 256, 0, stream>>>(vals, disp, seq, vbf, dummy);
      maskpv_kernel<<<NB * CV, 256, 0, stream>>>(vals, disp, seq, mask);
    }
    attn_fast<<<NB * (HWN / TM), 512, 0, stream>>>(kT, vbf, query, mask, out);
  }
}

// Round 9
// 227.234 us; speedup vs baseline: 1.4369x; 1.4369x over previous
//
#include <hip/hip_runtime.h>
#include <hip/hip_bf16.h>
#include <stdint.h>

// Problem constants
#define NS   8
#define NB   2
#define CK   64
#define CV   64
#define HWN  4096
#define SHW  32768
#define RADIUS_ 0.1f
#define MASK_W  6.103515625e-6f   // 0.2 / 8 / 64 / 64

// Tiling
#define TM    32
#define NW    8
#define QS_STR 68           // fp32 Q stage stride
#define P_STR  40           // bf16 P row stride (80 B, 16B-aligned)
#define SBIAS 24.0f
#define KS    4             // key splits

// Workspace layout
#define KT_ELEMS (NS * NB * CK * HWN)       // 4,194,304
#define KT_BYTES ((size_t)KT_ELEMS * 2)     // 8 MB fp16 transposed K
#define VB_BYTES ((size_t)KT_ELEMS * 2)     // 8 MB bf16 V
#define MASK_OFF (KT_BYTES + VB_BYTES)
#define WS_NEED  (MASK_OFF + (size_t)NB * CV * 4)
#define ONUM_OFF (MASK_OFF + 4096)
#define ONUM_BYTES ((size_t)KS * NB * HWN * CV * 4)          // 8.4 MB
#define ODEN_OFF (ONUM_OFF + ONUM_BYTES)
#define ODEN_BYTES ((size_t)KS * NB * HWN * 4)
#define WS2      (ODEN_OFF + ODEN_BYTES)                     // ~25.4 MB

typedef __bf16    bf16x8 __attribute__((ext_vector_type(8)));
typedef _Float16  f16x8  __attribute__((ext_vector_type(8)));
typedef float     f32x4  __attribute__((ext_vector_type(4)));
typedef unsigned short u16x8 __attribute__((ext_vector_type(8)));

__device__ __forceinline__ unsigned short f2bfu(float x) {
  __hip_bfloat16 h = __float2bfloat16(x);
  return __builtin_bit_cast(unsigned short, h);
}
__device__ __forceinline__ bf16x8 ld_bf8_lds(const unsigned short* p) {
  u16x8 u = *(const u16x8*)p;
  return __builtin_bit_cast(bf16x8, u);
}
// async global->LDS, 16B per lane; LDS dest = uniform base + lane*16
__device__ __forceinline__ void load_lds16(const void* g, void* l) {
  __builtin_amdgcn_global_load_lds(
      (const __attribute__((address_space(1))) unsigned int*)g,
      (__attribute__((address_space(3))) unsigned int*)l, 16, 0, 0);
}

// ---------------------------------------------------------------------------
// maskadd (fallback path)
// ---------------------------------------------------------------------------
__global__ __launch_bounds__(256) void maskpv_kernel(
    const float* __restrict__ vals, const float* __restrict__ disp,
    const int* __restrict__ seq, float* __restrict__ maskadd)
{
  const int b = blockIdx.x >> 6;
  const int v = blockIdx.x & 63;
  const int t = threadIdx.x;

  float dist[NS];
  #pragma unroll
  for (int s = 0; s < NS; ++s) {
    float i0 = (float)seq[(b * NS + s) * 2 + 0];
    float i1 = (float)seq[(b * NS + s) * 2 + 1];
    dist[s] = sqrtf((i1 - 5.f) * (i1 - 5.f) + (i0 - 5.f) * (i0 - 5.f));
  }
  float acc = 0.f;
  for (int hw = t; hw < HWN; hw += 256) {
    float dp = disp[b * HWN + hw];
    #pragma unroll
    for (int s = 0; s < NS; ++s)
      if (fabsf(dist[s] * dp) > RADIUS_)
        acc += vals[((size_t)((s * NB + b) * CV + v)) * HWN + hw];
  }
  #pragma unroll
  for (int m = 32; m >= 1; m >>= 1) acc += __shfl_xor(acc, m);
  __shared__ float red[4];
  if ((t & 63) == 0) red[t >> 6] = acc;
  __syncthreads();
  if (t == 0) maskadd[b * CV + v] = MASK_W * (red[0] + red[1] + red[2] + red[3]);
}

// ---------------------------------------------------------------------------
// Pre-pass: K fp32 [S,B,CK,HW] -> fp16 transposed kT[b][key][c]
// ---------------------------------------------------------------------------
#define PK_STR 72
__global__ __launch_bounds__(512) void prep_k(
    const float* __restrict__ keys, _Float16* __restrict__ kT)
{
  __shared__ _Float16 lds[256 * PK_STR];
  const int t     = threadIdx.x;
  const int blk   = blockIdx.x;
  const int chunk = blk & 15;
  const int s     = (blk >> 4) & 7;
  const int b     = blk >> 7;
  const int hw0   = chunk * 256;
  const int c_st  = t >> 3;
  const int msub  = (t & 7) * 8;

  const float* krow = keys + ((size_t)((s * NB + b) * CK + c_st)) * HWN + hw0;
  #pragma unroll
  for (int r = 0; r < 4; ++r) {
    const int m0 = msub + r * 64;
    f32x4 k0 = *(const f32x4*)(krow + m0);
    f32x4 k1 = *(const f32x4*)(krow + m0 + 4);
    #pragma unroll
    for (int j = 0; j < 4; ++j) {
      lds[(m0 + j)     * PK_STR + c_st] = (_Float16)k0[j];
      lds[(m0 + 4 + j) * PK_STR + c_st] = (_Float16)k1[j];
    }
  }
  __syncthreads();

  _Float16* kout = kT + ((size_t)(b * SHW + s * HWN + hw0)) * CK;
  const int mm = t >> 3, c0 = (t & 7) * 8;
  #pragma unroll
  for (int r2 = 0; r2 < 4; ++r2) {
    const int m = mm + r2 * 64;
    u16x8 v = *(const u16x8*)&lds[m * PK_STR + c0];
    *(u16x8*)(kout + (size_t)m * CK + c0) = v;
  }
}

// ---------------------------------------------------------------------------
// Pre-pass: V fp32 -> bf16 AND fused mask accumulation
// ---------------------------------------------------------------------------
__global__ __launch_bounds__(256) void prep_vm(
    const float* __restrict__ vals, const float* __restrict__ disp,
    const int* __restrict__ seq, unsigned short* __restrict__ vbf,
    float* __restrict__ maskadd)
{
  const int t  = threadIdx.x;
  const size_t i0 = (size_t)blockIdx.x * 2048;
  const int hw0 = (int)(i0 & 4095);
  const int c   = (int)((i0 >> 12) & 63);
  const int b   = (int)((i0 >> 18) & 1);
  const int s   = (int)(i0 >> 19);

  float j0 = (float)seq[(b * NS + s) * 2 + 0];
  float j1 = (float)seq[(b * NS + s) * 2 + 1];
  const float dist = sqrtf((j1 - 5.f) * (j1 - 5.f) + (j0 - 5.f) * (j0 - 5.f));

  const size_t i = i0 + (size_t)t * 8;
  const int hw = hw0 + t * 8;
  f32x4 a = *(const f32x4*)(vals + i);
  f32x4 bb = *(const f32x4*)(vals + i + 4);
  f32x4 d0 = *(const f32x4*)(disp + (size_t)b * HWN + hw);
  f32x4 d1 = *(const f32x4*)(disp + (size_t)b * HWN + hw + 4);
  u16x8 o;
  float acc = 0.f;
  #pragma unroll
  for (int j = 0; j < 4; ++j) {
    o[j]     = f2bfu(a[j]);
    o[4 + j] = f2bfu(bb[j]);
    if (fabsf(dist * d0[j]) > RADIUS_) acc += a[j];
    if (fabsf(dist * d1[j]) > RADIUS_) acc += bb[j];
  }
  *(u16x8*)(vbf + i) = o;

  #pragma unroll
  for (int m = 32; m >= 1; m >>= 1) acc += __shfl_xor(acc, m);
  __shared__ float red[4];
  if ((t & 63) == 0) red[t >> 6] = acc;
  __syncthreads();
  if (t == 0)
    atomicAdd(&maskadd[b * CV + c],
              MASK_W * (red[0] + red[1] + red[2] + red[3]));
}

// ---------------------------------------------------------------------------
// attn_v3: TM=64 rows/block, KS=4 key-split, XCD-L2 partition.
// K staged to LDS via global_load_lds (swizzled gather), shared by 8 waves.
// S^T MFMA order (A=K, B=Q) -> P writes become packed ds_write_b64.
// V direct from global. Partials -> onum/odenom.
// ---------------------------------------------------------------------------
struct __align__(16) Smem3 {
  union {
    struct {
      _Float16 kbuf[128 * 64];              // 16384 B swizzled K tile
      unsigned short p[NW][2][16 * P_STR];  // 20480 B P round-trip
    } main;
    struct {
      float obuf[4][32][64];                // 32768 B
      float dbuf[4][32];                    // 512 B
    } epi;
    float qs[64 * QS_STR];                  // 17408 B (prologue only)
  };
};

__global__ __launch_bounds__(512, 4) void attn_v3(
    const _Float16* __restrict__ kT,        // [B][SHW][CK] fp16
    const unsigned short* __restrict__ vbf, // [S,B,CV,HW] bf16
    const float* __restrict__ query,        // [B,CK,HW] fp32
    float* __restrict__ onum,               // [KS][B][HWN][CV]
    float* __restrict__ odenom)             // [KS][B][HWN]
{
  __shared__ Smem3 sm;
  const int t    = threadIdx.x;
  const int w    = t >> 6;
  const int lane = t & 63;
  const int quad = lane >> 4;
  const int l15  = lane & 15;
  const int kq   = w & 3;
  const int rg   = w >> 2;
  const int bidx = blockIdx.x;
  const int xcd  = bidx & 7;               // (ks<<1)|b -> one XCD per slice
  const int b    = xcd & 1;
  const int ks   = xcd >> 1;
  const int tile = bidx >> 3;              // 0..63
  const int n0   = tile * 64;

  // --- Stage Q (64 rows) transposed fp32, then fp16 B-fragments ---
  {
    const int qc   = t >> 3;
    const int noff = (t & 7) * 8;
    const int slot = qc ^ ((t & 7) << 2);
    const float* qp = query + (size_t)(b * CK + qc) * HWN + n0 + noff;
    f32x4 q0 = *(const f32x4*)(qp);
    f32x4 q1 = *(const f32x4*)(qp + 4);
    #pragma unroll
    for (int j = 0; j < 4; ++j) {
      sm.qs[(noff + j)     * QS_STR + slot] = q0[j];
      sm.qs[(noff + 4 + j) * QS_STR + slot] = q1[j];
    }
  }
  __syncthreads();
  f16x8 qf[2][2];
  #pragma unroll
  for (int f = 0; f < 2; ++f) {
    const int n  = rg * 32 + f * 16 + l15;
    const int sw = ((n >> 3) & 7) << 2;
    const float* base = &sm.qs[n * QS_STR];
    #pragma unroll
    for (int h = 0; h < 2; ++h) {
      const int c0 = (h * 32 + quad * 8) ^ sw;
      f32x4 a  = *(const f32x4*)(base + c0);
      f32x4 bb = *(const f32x4*)(base + (c0 ^ 4));
      f16x8 q;
      #pragma unroll
      for (int j = 0; j < 4; ++j) { q[j] = (_Float16)a[j]; q[4 + j] = (_Float16)bb[j]; }
      qf[f][h] = q;
    }
  }
  __syncthreads();  // qs aliases kbuf/p region

  f32x4 Of[2][4];
  f32x4 Ol[2];
  #pragma unroll
  for (int f = 0; f < 2; ++f) {
    #pragma unroll
    for (int cf = 0; cf < 4; ++cf) Of[f][cf] = (f32x4){0.f, 0.f, 0.f, 0.f};
    Ol[f] = (f32x4){0.f, 0.f, 0.f, 0.f};
  }
  bf16x8 vones;
  #pragma unroll
  for (int i = 0; i < 8; ++i)
    vones[i] = __builtin_bit_cast(__bf16, (unsigned short)0x3F80);

  // --- K staging: 16 KB tile = 16 DMA insts, 2 per wave; swizzled gather ---
  // LDS layout: kbuf[key][cq ^ (key&7)] in 16B chunks (8 fp16).
  uint32_t ksrc_off[2];
  char* klds[2];
  #pragma unroll
  for (int j = 0; j < 2; ++j) {
    const int inst = w * 2 + j;                 // 0..15
    const int kl   = inst * 8 + (lane >> 3);    // staged key 0..127
    const int cqs  = lane & 7;                  // LDS chunk slot
    ksrc_off[j] = (uint32_t)(kl * 128 + ((cqs ^ (kl & 7)) * 16));
    klds[j] = (char*)sm.main.kbuf + inst * 1024;
  }
  const char* kgbase = (const char*)(kT + (size_t)b * SHW * CK);
  const int   kbase0 = ks * (SHW / KS);

  for (int it = 0; it < 64; ++it) {
    const int key0 = kbase0 + it * 128;

    // --- issue K tile DMA (async) ---
    {
      const char* kg = kgbase + (size_t)key0 * 128;
      load_lds16(kg + ksrc_off[0], klds[0]);
      load_lds16(kg + ksrc_off[1], klds[1]);
    }

    // --- V B-fragments direct from global (bf16) ---
    const int sfrm = key0 >> 12;
    const int hwv  = (key0 & 4095) + kq * 32 + quad * 8;
    bf16x8 vf[4];
    #pragma unroll
    for (int cf = 0; cf < 4; ++cf)
      vf[cf] = ld_bf8_lds(vbf +
          ((size_t)((sfrm * NB + b) * CV + cf * 16 + l15)) * HWN + hwv);

    __syncthreads();  // K tile landed (barrier drains vmcnt)

    // --- K A-fragments from LDS (swizzled) ---
    f16x8 kf[2][2];
    #pragma unroll
    for (int g = 0; g < 2; ++g) {
      const int kl  = kq * 32 + g * 16 + l15;
      const int swz = kl & 7;
      const _Float16* kb = &sm.main.kbuf[kl * 64];
      #pragma unroll
      for (int h = 0; h < 2; ++h) {
        const int slot = (h * 4 + quad) ^ swz;
        kf[g][h] = *(const f16x8*)(kb + slot * 8);
      }
    }

    // --- S^T = K @ Q^T: D rows = key (quad*4+r), cols = qrow (l15) ---
    f32x4 sf[2][2];   // [g key-tile][f qrow-tile]
    #pragma unroll
    for (int g = 0; g < 2; ++g)
      #pragma unroll
      for (int f = 0; f < 2; ++f) {
        f32x4 acc = (f32x4){0.f, 0.f, 0.f, 0.f};
        acc = __builtin_amdgcn_mfma_f32_16x16x32_f16(kf[g][0], qf[f][0], acc, 0, 0, 0);
        acc = __builtin_amdgcn_mfma_f32_16x16x32_f16(kf[g][1], qf[f][1], acc, 0, 0, 0);
        sf[g][f] = acc;
      }

    // --- P = exp(S - SBIAS); pack 4 keys -> b64 LDS write (A-layout rows) ---
    #pragma unroll
    for (int g = 0; g < 2; ++g)
      #pragma unroll
      for (int f = 0; f < 2; ++f) {
        float e0 = __expf(sf[g][f][0] - SBIAS);
        float e1 = __expf(sf[g][f][1] - SBIAS);
        float e2 = __expf(sf[g][f][2] - SBIAS);
        float e3 = __expf(sf[g][f][3] - SBIAS);
        uint2 pk;
        pk.x = (unsigned)f2bfu(e0) | ((unsigned)f2bfu(e1) << 16);
        pk.y = (unsigned)f2bfu(e2) | ((unsigned)f2bfu(e3) << 16);
        // row = l15 (qrow), cols = g*16 + quad*4 .. +3 (keys)
        *(uint2*)((char*)&sm.main.p[w][f][0] + l15 * (P_STR * 2) + g * 32 + quad * 8) = pk;
      }
    asm volatile("s_waitcnt lgkmcnt(0)" ::: "memory");  // in-wave write->read
    bf16x8 pf[2];
    #pragma unroll
    for (int f = 0; f < 2; ++f)
      pf[f] = ld_bf8_lds(&sm.main.p[w][f][l15 * P_STR + quad * 8]);

    // --- O += P @ V, l += P @ 1 ---
    #pragma unroll
    for (int f = 0; f < 2; ++f) {
      #pragma unroll
      for (int cf = 0; cf < 4; ++cf)
        Of[f][cf] = __builtin_amdgcn_mfma_f32_16x16x32_bf16(pf[f], vf[cf], Of[f][cf], 0, 0, 0);
      Ol[f] = __builtin_amdgcn_mfma_f32_16x16x32_bf16(pf[f], vones, Ol[f], 0, 0, 0);
    }

    __syncthreads();  // retire kbuf reads before next DMA overwrites
  }

  // --- Epilogue: reduce 4 kq waves per rg phase, store partials ---
  #pragma unroll
  for (int phase = 0; phase < 2; ++phase) {
    if (rg == phase) {
      #pragma unroll
      for (int f = 0; f < 2; ++f)
        #pragma unroll
        for (int r = 0; r < 4; ++r) {
          const int row = f * 16 + quad * 4 + r;
          if (l15 == 0) sm.epi.dbuf[kq][row] = Ol[f][r];
          #pragma unroll
          for (int cf = 0; cf < 4; ++cf)
            sm.epi.obuf[kq][row][cf * 16 + l15] = Of[f][cf][r];
        }
    }
    __syncthreads();
    {
      const int row = t >> 4;
      const int v4  = (t & 15) * 4;
      f32x4 acc = *(const f32x4*)&sm.epi.obuf[0][row][v4];
      #pragma unroll
      for (int q = 1; q < 4; ++q)
        acc += *(const f32x4*)&sm.epi.obuf[q][row][v4];
      *(f32x4*)&onum[((size_t)(ks * NB + b) * HWN + n0 + phase * 32 + row) * CV + v4] = acc;
      if (t < 32) {
        float d = sm.epi.dbuf[0][t] + sm.epi.dbuf[1][t] +
                  sm.epi.dbuf[2][t] + sm.epi.dbuf[3][t];
        odenom[(size_t)(ks * NB + b) * HWN + n0 + phase * 32 + t] = d;
      }
    }
    __syncthreads();
  }
}

// ---------------------------------------------------------------------------
// Finalize: out[b][v][hw] = sum_ks onum / sum_ks odenom + mask
// ---------------------------------------------------------------------------
__global__ __launch_bounds__(256) void finalize_k(
    const float* __restrict__ onum, const float* __restrict__ odenom,
    const float* __restrict__ maskadd, float* __restrict__ out)
{
  __shared__ float tile[64][68];
  __shared__ float dinv[64];
  __shared__ float ml[64];
  const int t   = threadIdx.x;
  const int b   = blockIdx.x >> 6;
  const int hw0 = (blockIdx.x & 63) * 64;

  #pragma unroll
  for (int pass = 0; pass < 4; ++pass) {
    const int row = pass * 16 + (t >> 4);
    const int v4  = (t & 15) * 4;
    f32x4 acc = (f32x4){0.f, 0.f, 0.f, 0.f};
    #pragma unroll
    for (int ks = 0; ks < KS; ++ks)
      acc += *(const f32x4*)&onum[((size_t)(ks * NB + b) * HWN + hw0 + row) * CV + v4];
    *(f32x4*)&tile[row][v4] = acc;
  }
  if (t < 64) {
    float d = 0.f;
    #pragma unroll
    for (int ks = 0; ks < KS; ++ks)
      d += odenom[(size_t)(ks * NB + b) * HWN + hw0 + t];
    dinv[t] = 1.f / fmaxf(d, 1e-30f);
  }
  if (t >= 64 && t < 128) ml[t - 64] = maskadd[b * CV + (t - 64)];
  __syncthreads();

  #pragma unroll
  for (int pass = 0; pass < 4; ++pass) {
    const int v   = pass * 16 + (t >> 4);
    const int hw4 = (t & 15) * 4;
    f32x4 o;
    #pragma unroll
    for (int j = 0; j < 4; ++j)
      o[j] = tile[hw4 + j][v] * dinv[hw4 + j] + ml[v];
    *(f32x4*)&out[((size_t)(b * CV + v)) * HWN + hw0 + hw4] = o;
  }
}

// ---------------------------------------------------------------------------
// Round-6 attention (fallback, small ws)
// ---------------------------------------------------------------------------
struct __align__(16) SmemF {
  union {
    float qs[TM * QS_STR];
    unsigned short p[NW][2][16 * P_STR];
    struct {
      float obuf[NW][TM][CV];
      float lbuf[NW][TM];
    } epi;
  };
};

__global__ __launch_bounds__(512) void attn_fast(
    const _Float16* __restrict__ kT, const unsigned short* __restrict__ vbf,
    const float* __restrict__ query, const float* __restrict__ maskadd,
    float* __restrict__ out)
{
  __shared__ SmemF sm;
  const int t    = threadIdx.x;
  const int w    = t >> 6;
  const int lane = t & 63;
  const int quad = lane >> 4;
  const int l15  = lane & 15;
  const int bidx = blockIdx.x;
  const int b    = bidx & 1;
  const int n0   = ((bidx >> 1) & 127) * TM;

  if (t < 256) {
    const int qc   = t >> 2;
    const int noff = (t & 3) * 8;
    const int slot = qc ^ ((t & 3) << 2);
    const float* qp = query + (size_t)(b * CK + qc) * HWN + n0 + noff;
    f32x4 q0 = *(const f32x4*)(qp);
    f32x4 q1 = *(const f32x4*)(qp + 4);
    #pragma unroll
    for (int j = 0; j < 4; ++j) {
      sm.qs[(noff + j)     * QS_STR + slot] = q0[j];
      sm.qs[(noff + 4 + j) * QS_STR + slot] = q1[j];
    }
  }
  __syncthreads();
  f16x8 qf[2][2];
  #pragma unroll
  for (int f = 0; f < 2; ++f) {
    const int n  = f * 16 + l15;
    const int sw = ((n >> 3) & 7) << 2;
    const float* base = &sm.qs[n * QS_STR];
    #pragma unroll
    for (int h = 0; h < 2; ++h) {
      const int c0 = (h * 32 + quad * 8) ^ sw;
      f32x4 a  = *(const f32x4*)(base + c0);
      f32x4 bb = *(const f32x4*)(base + (c0 ^ 4));
      f16x8 q;
      #pragma unroll
      for (int j = 0; j < 4; ++j) { q[j] = (_Float16)a[j]; q[4 + j] = (_Float16)bb[j]; }
      qf[f][h] = q;
    }
  }
  __syncthreads();

  f32x4 Of[2][4];
  f32x4 Ol[2];
  #pragma unroll
  for (int f = 0; f < 2; ++f) {
    #pragma unroll
    for (int cf = 0; cf < 4; ++cf) Of[f][cf] = (f32x4){0.f, 0.f, 0.f, 0.f};
    Ol[f] = (f32x4){0.f, 0.f, 0.f, 0.f};
  }
  bf16x8 vones;
  #pragma unroll
  for (int i = 0; i < 8; ++i)
    vones[i] = __builtin_bit_cast(__bf16, (unsigned short)0x3F80);

  const _Float16* kbase = kT + (size_t)b * SHW * CK;

  for (int it = 0; it < SHW / 256; ++it) {
    const int key0 = it * 256 + w * 32;
    f16x8 kf[2][2];
    #pragma unroll
    for (int g = 0; g < 2; ++g)
      #pragma unroll
      for (int h = 0; h < 2; ++h)
        kf[g][h] = *(const f16x8*)(kbase +
            (size_t)(key0 + g * 16 + l15) * CK + h * 32 + quad * 8);

    const int s   = it >> 4;
    const int hwv = (it & 15) * 256 + w * 32 + quad * 8;
    bf16x8 vf[4];
    #pragma unroll
    for (int cf = 0; cf < 4; ++cf)
      vf[cf] = ld_bf8_lds(vbf +
          ((size_t)((s * NB + b) * CV + cf * 16 + l15)) * HWN + hwv);

    f32x4 sfv[2][2];
    #pragma unroll
    for (int f = 0; f < 2; ++f)
      #pragma unroll
      for (int g = 0; g < 2; ++g) {
        f32x4 acc = (f32x4){0.f, 0.f, 0.f, 0.f};
        acc = __builtin_amdgcn_mfma_f32_16x16x32_f16(qf[f][0], kf[g][0], acc, 0, 0, 0);
        acc = __builtin_amdgcn_mfma_f32_16x16x32_f16(qf[f][1], kf[g][1], acc, 0, 0, 0);
        sfv[f][g] = acc;
      }

    #pragma unroll
    for (int f = 0; f < 2; ++f)
      #pragma unroll
      for (int g = 0; g < 2; ++g)
        #pragma unroll
        for (int r = 0; r < 4; ++r)
          sfv[f][g][r] = __expf(sfv[f][g][r] - SBIAS);

    #pragma unroll
    for (int f = 0; f < 2; ++f)
      #pragma unroll
      for (int g = 0; g < 2; ++g)
        #pragma unroll
        for (int r = 0; r < 4; ++r)
          sm.p[w][f][(quad * 4 + r) * P_STR + g * 16 + l15] = f2bfu(sfv[f][g][r]);
    asm volatile("s_waitcnt lgkmcnt(0)" ::: "memory");
    bf16x8 pf[2];
    #pragma unroll
    for (int f = 0; f < 2; ++f)
      pf[f] = ld_bf8_lds(&sm.p[w][f][l15 * P_STR + quad * 8]);

    #pragma unroll
    for (int f = 0; f < 2; ++f) {
      #pragma unroll
      for (int cf = 0; cf < 4; ++cf)
        Of[f][cf] = __builtin_amdgcn_mfma_f32_16x16x32_bf16(pf[f], vf[cf], Of[f][cf], 0, 0, 0);
      Ol[f] = __builtin_amdgcn_mfma_f32_16x16x32_bf16(pf[f], vones, Ol[f], 0, 0, 0);
    }
  }

  __syncthreads();
  #pragma unroll
  for (int f = 0; f < 2; ++f)
    #pragma unroll
    for (int r = 0; r < 4; ++r) {
      const int row = f * 16 + quad * 4 + r;
      if (l15 == 0) sm.epi.lbuf[w][row] = Ol[f][r];
      #pragma unroll
      for (int cf = 0; cf < 4; ++cf)
        sm.epi.obuf[w][row][cf * 16 + l15] = Of[f][cf][r];
    }
  __syncthreads();
  {
    const int n   = t & 31;
    const int vhi = t >> 5;
    float denom = 0.f;
    #pragma unroll
    for (int ww = 0; ww < NW; ++ww) denom += sm.epi.lbuf[ww][n];
    const float inv = 1.f / fmaxf(denom, 1e-30f);
    #pragma unroll
    for (int g = 0; g < 4; ++g) {
      const int v = vhi + 16 * g;
      float num = 0.f;
      #pragma unroll
      for (int ww = 0; ww < NW; ++ww) num += sm.epi.obuf[ww][n][v];
      out[((size_t)(b * CV + v)) * HWN + n0 + n] = num * inv + maskadd[b * CV + v];
    }
  }
}

// ---------------------------------------------------------------------------
extern "C" void kernel_launch(void* const* d_in, const int* in_sizes, int n_in,
                              void* d_out, int out_size, void* d_ws, size_t ws_size,
                              hipStream_t stream) {
  const float* keys  = (const float*)d_in[0];
  const float* vals  = (const float*)d_in[1];
  const float* query = (const float*)d_in[2];
  const float* disp  = (const float*)d_in[3];
  const int*   seq   = (const int*)d_in[4];
  float*       out   = (float*)d_out;

  _Float16*       kT   = (_Float16*)d_ws;
  unsigned short* vbf  = (unsigned short*)((char*)d_ws + KT_BYTES);
  float*          mask = (float*)((char*)d_ws + MASK_OFF);

  if (ws_size >= WS2) {
    float* onum   = (float*)((char*)d_ws + ONUM_OFF);
    float* odenom = (float*)((char*)d_ws + ODEN_OFF);
    hipMemsetAsync(mask, 0, (size_t)NB * CV * 4, stream);
    prep_k<<<NB * NS * 16, 512, 0, stream>>>(keys, kT);
    prep_vm<<<KT_ELEMS / 2048, 256, 0, stream>>>(vals, disp, seq, vbf, mask);
    attn_v3<<<NB * 64 * KS, 512, 0, stream>>>(kT, vbf, query, onum, odenom);
    finalize_k<<<NB * (HWN / 64), 256, 0, stream>>>(onum, odenom, mask, out);
  } else {
    prep_k<<<NB * NS * 16, 512, 0, stream>>>(keys, kT);
    maskpv_kernel<<<NB * CV, 256, 0, stream>>>(vals, disp, seq, mask);
    {
      float* dummy = mask;
      prep_vm<<<KT_ELEMS / 2048, 256, 0, stream>>>(vals, disp, seq, vbf, dummy);
      maskpv_kernel<<<NB * CV, 256, 0, stream>>>(vals, disp, seq, mask);
    }
    attn_fast<<<NB * (HWN / TM), 512, 0, stream>>>(kT, vbf, query, mask, out);
  }
}

// Round 10
// 220.315 us; speedup vs baseline: 1.4820x; 1.0314x over previous
//
#include <hip/hip_runtime.h>
#include <hip/hip_bf16.h>
#include <stdint.h>

// Problem constants
#define NS   8
#define NB   2
#define CK   64
#define CV   64
#define HWN  4096
#define SHW  32768
#define RADIUS_ 0.1f
#define MASK_W  6.103515625e-6f   // 0.2 / 8 / 64 / 64

// Tiling
#define TM    32
#define NW    8
#define QS_STR 68           // fp32 Q stage stride
#define P_STR  40           // bf16 P row stride (80 B, 16B-aligned)
#define SBIAS 24.0f
#define KS    4             // key splits

// Workspace layout
#define KT_ELEMS (NS * NB * CK * HWN)       // 4,194,304
#define KT_BYTES ((size_t)KT_ELEMS * 2)     // 8 MB fp16 transposed K
#define VB_BYTES ((size_t)KT_ELEMS * 2)     // 8 MB bf16 V
#define MASK_OFF (KT_BYTES + VB_BYTES)
#define WS_NEED  (MASK_OFF + (size_t)NB * CV * 4)
#define ONUM_OFF (MASK_OFF + 4096)
#define ONUM_BYTES ((size_t)KS * NB * HWN * CV * 4)          // 8.4 MB
#define ODEN_OFF (ONUM_OFF + ONUM_BYTES)
#define ODEN_BYTES ((size_t)KS * NB * HWN * 4)
#define WS2      (ODEN_OFF + ODEN_BYTES)                     // ~25.4 MB

typedef __bf16    bf16x8 __attribute__((ext_vector_type(8)));
typedef _Float16  f16x8  __attribute__((ext_vector_type(8)));
typedef float     f32x4  __attribute__((ext_vector_type(4)));
typedef unsigned short u16x8 __attribute__((ext_vector_type(8)));

__device__ __forceinline__ unsigned short f2bfu(float x) {
  __hip_bfloat16 h = __float2bfloat16(x);
  return __builtin_bit_cast(unsigned short, h);
}
__device__ __forceinline__ bf16x8 ld_bf8_lds(const unsigned short* p) {
  u16x8 u = *(const u16x8*)p;
  return __builtin_bit_cast(bf16x8, u);
}
// async global->LDS, 16B per lane; LDS dest = wave-uniform base + lane*16
__device__ __forceinline__ void load_lds16(const void* g, void* l) {
  __builtin_amdgcn_global_load_lds(
      (const __attribute__((address_space(1))) unsigned int*)g,
      (__attribute__((address_space(3))) unsigned int*)l, 16, 0, 0);
}

// ---------------------------------------------------------------------------
// Fused pre-pass:
//   blocks [0,256):    K fp32 [S,B,CK,HW] -> fp16 transposed kT[b][key][c]
//   blocks [256,1280): V fp32 -> bf16 (layout kept) + fused mask atomicAdd
// ---------------------------------------------------------------------------
#define PK_STR 72
__global__ __launch_bounds__(512) void prep_all(
    const float* __restrict__ keys, const float* __restrict__ vals,
    const float* __restrict__ disp, const int* __restrict__ seq,
    _Float16* __restrict__ kT, unsigned short* __restrict__ vbf,
    float* __restrict__ maskadd)
{
  const int t = threadIdx.x;
  const int blk = blockIdx.x;
  if (blk < 256) {
    __shared__ _Float16 lds[256 * PK_STR];
    const int chunk = blk & 15;
    const int s     = (blk >> 4) & 7;
    const int b     = blk >> 7;
    const int hw0   = chunk * 256;
    const int c_st  = t >> 3;
    const int msub  = (t & 7) * 8;

    const float* krow = keys + ((size_t)((s * NB + b) * CK + c_st)) * HWN + hw0;
    #pragma unroll
    for (int r = 0; r < 4; ++r) {
      const int m0 = msub + r * 64;
      f32x4 k0 = *(const f32x4*)(krow + m0);
      f32x4 k1 = *(const f32x4*)(krow + m0 + 4);
      #pragma unroll
      for (int j = 0; j < 4; ++j) {
        lds[(m0 + j)     * PK_STR + c_st] = (_Float16)k0[j];
        lds[(m0 + 4 + j) * PK_STR + c_st] = (_Float16)k1[j];
      }
    }
    __syncthreads();

    _Float16* kout = kT + ((size_t)(b * SHW + s * HWN + hw0)) * CK;
    const int mm = t >> 3, c0 = (t & 7) * 8;
    #pragma unroll
    for (int r2 = 0; r2 < 4; ++r2) {
      const int m = mm + r2 * 64;
      u16x8 v = *(const u16x8*)&lds[m * PK_STR + c0];
      *(u16x8*)(kout + (size_t)m * CK + c0) = v;
    }
  } else {
    // V path: one (s,b,c) row of 4096 elems per block
    const int r = blk - 256;           // 0..1023
    const int s = r >> 7;
    const int b = (r >> 6) & 1;
    const int c = r & 63;
    float j0 = (float)seq[(b * NS + s) * 2 + 0];
    float j1 = (float)seq[(b * NS + s) * 2 + 1];
    const float dist = sqrtf((j1 - 5.f) * (j1 - 5.f) + (j0 - 5.f) * (j0 - 5.f));

    const size_t i = (size_t)r * HWN + t * 8;
    const int hw = t * 8;
    f32x4 a  = *(const f32x4*)(vals + i);
    f32x4 bb = *(const f32x4*)(vals + i + 4);
    f32x4 d0 = *(const f32x4*)(disp + (size_t)b * HWN + hw);
    f32x4 d1 = *(const f32x4*)(disp + (size_t)b * HWN + hw + 4);
    u16x8 o;
    float acc = 0.f;
    #pragma unroll
    for (int j = 0; j < 4; ++j) {
      o[j]     = f2bfu(a[j]);
      o[4 + j] = f2bfu(bb[j]);
      if (fabsf(dist * d0[j]) > RADIUS_) acc += a[j];
      if (fabsf(dist * d1[j]) > RADIUS_) acc += bb[j];
    }
    *(u16x8*)(vbf + i) = o;

    #pragma unroll
    for (int m = 32; m >= 1; m >>= 1) acc += __shfl_xor(acc, m);
    __shared__ float red[8];
    if ((t & 63) == 0) red[t >> 6] = acc;
    __syncthreads();
    if (t == 0) {
      float s8 = 0.f;
      #pragma unroll
      for (int j = 0; j < 8; ++j) s8 += red[j];
      atomicAdd(&maskadd[b * CV + c], MASK_W * s8);
    }
  }
}

// ---------------------------------------------------------------------------
// attn_v4: TM=64, KS=4, XCD-L2 partition, double-buffered K-tile DMA
// (prefetch issued after the barrier -> latency hidden by compute), S^T MFMA,
// truncation-packed P b64 round-trip, V direct from global.
// ---------------------------------------------------------------------------
struct __align__(16) Smem4 {
  union {
    struct {
      _Float16 kbuf[2][128 * 64];           // 32768 B (double-buffered K tile)
      unsigned short p[NW][2][16 * P_STR];  // 20480 B P round-trip
    } main;
    struct {
      float obuf[4][32][64];                // 32768 B
      float dbuf[4][32];                    // 512 B
    } epi;
    float qs[64 * QS_STR];                  // 17408 B (prologue only)
  };
};

__global__ __launch_bounds__(512, 4) void attn_v4(
    const _Float16* __restrict__ kT,        // [B][SHW][CK] fp16
    const unsigned short* __restrict__ vbf, // [S,B,CV,HW] bf16
    const float* __restrict__ query,        // [B,CK,HW] fp32
    float* __restrict__ onum,               // [KS][B][HWN][CV]
    float* __restrict__ odenom)             // [KS][B][HWN]
{
  __shared__ Smem4 sm;
  const int t    = threadIdx.x;
  const int w    = t >> 6;
  const int lane = t & 63;
  const int quad = lane >> 4;
  const int l15  = lane & 15;
  const int kq   = w & 3;
  const int rg   = w >> 2;
  const int bidx = blockIdx.x;
  const int xcd  = bidx & 7;               // (ks<<1)|b -> one XCD per K/V slice
  const int b    = xcd & 1;
  const int ks   = xcd >> 1;
  const int tile = bidx >> 3;              // 0..63
  const int n0   = tile * 64;

  // --- Stage Q (64 rows) transposed fp32, then fp16 B-fragments ---
  {
    const int qc   = t >> 3;
    const int noff = (t & 7) * 8;
    const int slot = qc ^ ((t & 7) << 2);
    const float* qp = query + (size_t)(b * CK + qc) * HWN + n0 + noff;
    f32x4 q0 = *(const f32x4*)(qp);
    f32x4 q1 = *(const f32x4*)(qp + 4);
    #pragma unroll
    for (int j = 0; j < 4; ++j) {
      sm.qs[(noff + j)     * QS_STR + slot] = q0[j];
      sm.qs[(noff + 4 + j) * QS_STR + slot] = q1[j];
    }
  }
  __syncthreads();
  f16x8 qf[2][2];
  #pragma unroll
  for (int f = 0; f < 2; ++f) {
    const int n  = rg * 32 + f * 16 + l15;
    const int sw = ((n >> 3) & 7) << 2;
    const float* base = &sm.qs[n * QS_STR];
    #pragma unroll
    for (int h = 0; h < 2; ++h) {
      const int c0 = (h * 32 + quad * 8) ^ sw;
      f32x4 a  = *(const f32x4*)(base + c0);
      f32x4 bb = *(const f32x4*)(base + (c0 ^ 4));
      f16x8 q;
      #pragma unroll
      for (int j = 0; j < 4; ++j) { q[j] = (_Float16)a[j]; q[4 + j] = (_Float16)bb[j]; }
      qf[f][h] = q;
    }
  }
  __syncthreads();  // qs reads done; kbuf region free for DMA

  f32x4 Of[2][4];
  f32x4 Ol[2];
  #pragma unroll
  for (int f = 0; f < 2; ++f) {
    #pragma unroll
    for (int cf = 0; cf < 4; ++cf) Of[f][cf] = (f32x4){0.f, 0.f, 0.f, 0.f};
    Ol[f] = (f32x4){0.f, 0.f, 0.f, 0.f};
  }
  bf16x8 vones;
  #pragma unroll
  for (int i = 0; i < 8; ++i)
    vones[i] = __builtin_bit_cast(__bf16, (unsigned short)0x3F80);

  // DMA addressing: 16 insts/tile (2 per wave), swizzled gather.
  // LDS layout: kbuf[c][key][cq ^ (key&7)] in 16B chunks.
  uint32_t ksrc_off[2];
  int      ldsoff[2];
  #pragma unroll
  for (int j = 0; j < 2; ++j) {
    const int inst = w * 2 + j;                 // 0..15
    const int kl   = inst * 8 + (lane >> 3);    // staged key 0..127
    const int cqs  = lane & 7;
    ksrc_off[j] = (uint32_t)(kl * 128 + ((cqs ^ (kl & 7)) * 16));
    ldsoff[j]   = inst * 1024;
  }
  const char* kgbase = (const char*)(kT + (size_t)b * SHW * CK);
  const int   kbase0 = ks * (SHW / KS);

  // Prologue: DMA tile 0 into buf 0
  {
    const char* kg = kgbase + (size_t)kbase0 * 128;
    load_lds16(kg + ksrc_off[0], (char*)sm.main.kbuf[0] + ldsoff[0]);
    load_lds16(kg + ksrc_off[1], (char*)sm.main.kbuf[0] + ldsoff[1]);
  }

  for (int it = 0; it < 64; ++it) {
    const int cur  = it & 1;
    const int key0 = kbase0 + it * 128;

    __syncthreads();  // drains vmcnt: tile `it` landed; buf[cur^1] free

    // --- prefetch tile it+1 into the other buffer (hidden by this compute) ---
    if (it < 63) {
      const char* kg = kgbase + (size_t)(key0 + 128) * 128;
      load_lds16(kg + ksrc_off[0], (char*)sm.main.kbuf[cur ^ 1] + ldsoff[0]);
      load_lds16(kg + ksrc_off[1], (char*)sm.main.kbuf[cur ^ 1] + ldsoff[1]);
    }

    // --- V B-fragments direct from global (bf16) ---
    const int sfrm = key0 >> 12;
    const int hwv  = (key0 & 4095) + kq * 32 + quad * 8;
    bf16x8 vf[4];
    #pragma unroll
    for (int cf = 0; cf < 4; ++cf)
      vf[cf] = ld_bf8_lds(vbf +
          ((size_t)((sfrm * NB + b) * CV + cf * 16 + l15)) * HWN + hwv);

    // --- K A-fragments from LDS (swizzled) ---
    f16x8 kf[2][2];
    #pragma unroll
    for (int g = 0; g < 2; ++g) {
      const int kl  = kq * 32 + g * 16 + l15;
      const int swz = kl & 7;
      const _Float16* kb = &sm.main.kbuf[cur][kl * 64];
      #pragma unroll
      for (int h = 0; h < 2; ++h) {
        const int slot = (h * 4 + quad) ^ swz;
        kf[g][h] = *(const f16x8*)(kb + slot * 8);
      }
    }

    // --- S^T = K @ Q^T: D rows = key (quad*4+r), cols = qrow (l15) ---
    f32x4 sf[2][2];
    #pragma unroll
    for (int g = 0; g < 2; ++g)
      #pragma unroll
      for (int f = 0; f < 2; ++f) {
        f32x4 acc = (f32x4){0.f, 0.f, 0.f, 0.f};
        acc = __builtin_amdgcn_mfma_f32_16x16x32_f16(kf[g][0], qf[f][0], acc, 0, 0, 0);
        acc = __builtin_amdgcn_mfma_f32_16x16x32_f16(kf[g][1], qf[f][1], acc, 0, 0, 0);
        sf[g][f] = acc;
      }

    // --- P = exp(S - SBIAS), truncation-packed to bf16 pairs -> b64 writes ---
    #pragma unroll
    for (int g = 0; g < 2; ++g)
      #pragma unroll
      for (int f = 0; f < 2; ++f) {
        float e0 = __expf(sf[g][f][0] - SBIAS);
        float e1 = __expf(sf[g][f][1] - SBIAS);
        float e2 = __expf(sf[g][f][2] - SBIAS);
        float e3 = __expf(sf[g][f][3] - SBIAS);
        uint2 pk;
        pk.x = (__builtin_bit_cast(unsigned, e0) >> 16) |
               (__builtin_bit_cast(unsigned, e1) & 0xFFFF0000u);
        pk.y = (__builtin_bit_cast(unsigned, e2) >> 16) |
               (__builtin_bit_cast(unsigned, e3) & 0xFFFF0000u);
        *(uint2*)((char*)&sm.main.p[w][f][0] + l15 * (P_STR * 2) + g * 32 + quad * 8) = pk;
      }
    asm volatile("s_waitcnt lgkmcnt(0)" ::: "memory");  // in-wave write->read
    bf16x8 pf[2];
    #pragma unroll
    for (int f = 0; f < 2; ++f)
      pf[f] = ld_bf8_lds(&sm.main.p[w][f][l15 * P_STR + quad * 8]);

    // --- O += P @ V, l += P @ 1 ---
    #pragma unroll
    for (int f = 0; f < 2; ++f) {
      #pragma unroll
      for (int cf = 0; cf < 4; ++cf)
        Of[f][cf] = __builtin_amdgcn_mfma_f32_16x16x32_bf16(pf[f], vf[cf], Of[f][cf], 0, 0, 0);
      Ol[f] = __builtin_amdgcn_mfma_f32_16x16x32_bf16(pf[f], vones, Ol[f], 0, 0, 0);
    }
  }

  __syncthreads();  // all waves done with kbuf/p before epi alias

  // --- Epilogue: reduce 4 kq waves per rg phase, store partials ---
  #pragma unroll
  for (int phase = 0; phase < 2; ++phase) {
    if (rg == phase) {
      #pragma unroll
      for (int f = 0; f < 2; ++f)
        #pragma unroll
        for (int r = 0; r < 4; ++r) {
          const int row = f * 16 + quad * 4 + r;
          if (l15 == 0) sm.epi.dbuf[kq][row] = Ol[f][r];
          #pragma unroll
          for (int cf = 0; cf < 4; ++cf)
            sm.epi.obuf[kq][row][cf * 16 + l15] = Of[f][cf][r];
        }
    }
    __syncthreads();
    {
      const int row = t >> 4;
      const int v4  = (t & 15) * 4;
      f32x4 acc = *(const f32x4*)&sm.epi.obuf[0][row][v4];
      #pragma unroll
      for (int q = 1; q < 4; ++q)
        acc += *(const f32x4*)&sm.epi.obuf[q][row][v4];
      *(f32x4*)&onum[((size_t)(ks * NB + b) * HWN + n0 + phase * 32 + row) * CV + v4] = acc;
      if (t < 32) {
        float d = sm.epi.dbuf[0][t] + sm.epi.dbuf[1][t] +
                  sm.epi.dbuf[2][t] + sm.epi.dbuf[3][t];
        odenom[(size_t)(ks * NB + b) * HWN + n0 + phase * 32 + t] = d;
      }
    }
    __syncthreads();
  }
}

// ---------------------------------------------------------------------------
// Finalize: out[b][v][hw] = sum_ks onum / sum_ks odenom + mask
// ---------------------------------------------------------------------------
__global__ __launch_bounds__(256) void finalize_k(
    const float* __restrict__ onum, const float* __restrict__ odenom,
    const float* __restrict__ maskadd, float* __restrict__ out)
{
  __shared__ float tile[64][68];
  __shared__ float dinv[64];
  __shared__ float ml[64];
  const int t   = threadIdx.x;
  const int b   = blockIdx.x >> 6;
  const int hw0 = (blockIdx.x & 63) * 64;

  #pragma unroll
  for (int pass = 0; pass < 4; ++pass) {
    const int row = pass * 16 + (t >> 4);
    const int v4  = (t & 15) * 4;
    f32x4 acc = (f32x4){0.f, 0.f, 0.f, 0.f};
    #pragma unroll
    for (int ks = 0; ks < KS; ++ks)
      acc += *(const f32x4*)&onum[((size_t)(ks * NB + b) * HWN + hw0 + row) * CV + v4];
    *(f32x4*)&tile[row][v4] = acc;
  }
  if (t < 64) {
    float d = 0.f;
    #pragma unroll
    for (int ks = 0; ks < KS; ++ks)
      d += odenom[(size_t)(ks * NB + b) * HWN + hw0 + t];
    dinv[t] = 1.f / fmaxf(d, 1e-30f);
  }
  if (t >= 64 && t < 128) ml[t - 64] = maskadd[b * CV + (t - 64)];
  __syncthreads();

  #pragma unroll
  for (int pass = 0; pass < 4; ++pass) {
    const int v   = pass * 16 + (t >> 4);
    const int hw4 = (t & 15) * 4;
    f32x4 o;
    #pragma unroll
    for (int j = 0; j < 4; ++j)
      o[j] = tile[hw4 + j][v] * dinv[hw4 + j] + ml[v];
    *(f32x4*)&out[((size_t)(b * CV + v)) * HWN + hw0 + hw4] = o;
  }
}

// ---------------------------------------------------------------------------
// Round-6 attention (fallback, small ws)
// ---------------------------------------------------------------------------
struct __align__(16) SmemF {
  union {
    float qs[TM * QS_STR];
    unsigned short p[NW][2][16 * P_STR];
    struct {
      float obuf[NW][TM][CV];
      float lbuf[NW][TM];
    } epi;
  };
};

__global__ __launch_bounds__(512) void attn_fast(
    const _Float16* __restrict__ kT, const unsigned short* __restrict__ vbf,
    const float* __restrict__ query, const float* __restrict__ maskadd,
    float* __restrict__ out)
{
  __shared__ SmemF sm;
  const int t    = threadIdx.x;
  const int w    = t >> 6;
  const int lane = t & 63;
  const int quad = lane >> 4;
  const int l15  = lane & 15;
  const int bidx = blockIdx.x;
  const int b    = bidx & 1;
  const int n0   = ((bidx >> 1) & 127) * TM;

  if (t < 256) {
    const int qc   = t >> 2;
    const int noff = (t & 3) * 8;
    const int slot = qc ^ ((t & 3) << 2);
    const float* qp = query + (size_t)(b * CK + qc) * HWN + n0 + noff;
    f32x4 q0 = *(const f32x4*)(qp);
    f32x4 q1 = *(const f32x4*)(qp + 4);
    #pragma unroll
    for (int j = 0; j < 4; ++j) {
      sm.qs[(noff + j)     * QS_STR + slot] = q0[j];
      sm.qs[(noff + 4 + j) * QS_STR + slot] = q1[j];
    }
  }
  __syncthreads();
  f16x8 qf[2][2];
  #pragma unroll
  for (int f = 0; f < 2; ++f) {
    const int n  = f * 16 + l15;
    const int sw = ((n >> 3) & 7) << 2;
    const float* base = &sm.qs[n * QS_STR];
    #pragma unroll
    for (int h = 0; h < 2; ++h) {
      const int c0 = (h * 32 + quad * 8) ^ sw;
      f32x4 a  = *(const f32x4*)(base + c0);
      f32x4 bb = *(const f32x4*)(base + (c0 ^ 4));
      f16x8 q;
      #pragma unroll
      for (int j = 0; j < 4; ++j) { q[j] = (_Float16)a[j]; q[4 + j] = (_Float16)bb[j]; }
      qf[f][h] = q;
    }
  }
  __syncthreads();

  f32x4 Of[2][4];
  f32x4 Ol[2];
  #pragma unroll
  for (int f = 0; f < 2; ++f) {
    #pragma unroll
    for (int cf = 0; cf < 4; ++cf) Of[f][cf] = (f32x4){0.f, 0.f, 0.f, 0.f};
    Ol[f] = (f32x4){0.f, 0.f, 0.f, 0.f};
  }
  bf16x8 vones;
  #pragma unroll
  for (int i = 0; i < 8; ++i)
    vones[i] = __builtin_bit_cast(__bf16, (unsigned short)0x3F80);

  const _Float16* kbase = kT + (size_t)b * SHW * CK;

  for (int it = 0; it < SHW / 256; ++it) {
    const int key0 = it * 256 + w * 32;
    f16x8 kf[2][2];
    #pragma unroll
    for (int g = 0; g < 2; ++g)
      #pragma unroll
      for (int h = 0; h < 2; ++h)
        kf[g][h] = *(const f16x8*)(kbase +
            (size_t)(key0 + g * 16 + l15) * CK + h * 32 + quad * 8);

    const int s   = it >> 4;
    const int hwv = (it & 15) * 256 + w * 32 + quad * 8;
    bf16x8 vf[4];
    #pragma unroll
    for (int cf = 0; cf < 4; ++cf)
      vf[cf] = ld_bf8_lds(vbf +
          ((size_t)((s * NB + b) * CV + cf * 16 + l15)) * HWN + hwv);

    f32x4 sfv[2][2];
    #pragma unroll
    for (int f = 0; f < 2; ++f)
      #pragma unroll
      for (int g = 0; g < 2; ++g) {
        f32x4 acc = (f32x4){0.f, 0.f, 0.f, 0.f};
        acc = __builtin_amdgcn_mfma_f32_16x16x32_f16(qf[f][0], kf[g][0], acc, 0, 0, 0);
        acc = __builtin_amdgcn_mfma_f32_16x16x32_f16(qf[f][1], kf[g][1], acc, 0, 0, 0);
        sfv[f][g] = acc;
      }

    #pragma unroll
    for (int f = 0; f < 2; ++f)
      #pragma unroll
      for (int g = 0; g < 2; ++g)
        #pragma unroll
        for (int r = 0; r < 4; ++r)
          sfv[f][g][r] = __expf(sfv[f][g][r] - SBIAS);

    #pragma unroll
    for (int f = 0; f < 2; ++f)
      #pragma unroll
      for (int g = 0; g < 2; ++g)
        #pragma unroll
        for (int r = 0; r < 4; ++r)
          sm.p[w][f][(quad * 4 + r) * P_STR + g * 16 + l15] = f2bfu(sfv[f][g][r]);
    asm volatile("s_waitcnt lgkmcnt(0)" ::: "memory");
    bf16x8 pf[2];
    #pragma unroll
    for (int f = 0; f < 2; ++f)
      pf[f] = ld_bf8_lds(&sm.p[w][f][l15 * P_STR + quad * 8]);

    #pragma unroll
    for (int f = 0; f < 2; ++f) {
      #pragma unroll
      for (int cf = 0; cf < 4; ++cf)
        Of[f][cf] = __builtin_amdgcn_mfma_f32_16x16x32_bf16(pf[f], vf[cf], Of[f][cf], 0, 0, 0);
      Ol[f] = __builtin_amdgcn_mfma_f32_16x16x32_bf16(pf[f], vones, Ol[f], 0, 0, 0);
    }
  }

  __syncthreads();
  #pragma unroll
  for (int f = 0; f < 2; ++f)
    #pragma unroll
    for (int r = 0; r < 4; ++r) {
      const int row = f * 16 + quad * 4 + r;
      if (l15 == 0) sm.epi.lbuf[w][row] = Ol[f][r];
      #pragma unroll
      for (int cf = 0; cf < 4; ++cf)
        sm.epi.obuf[w][row][cf * 16 + l15] = Of[f][cf][r];
    }
  __syncthreads();
  {
    const int n   = t & 31;
    const int vhi = t >> 5;
    float denom = 0.f;
    #pragma unroll
    for (int ww = 0; ww < NW; ++ww) denom += sm.epi.lbuf[ww][n];
    const float inv = 1.f / fmaxf(denom, 1e-30f);
    #pragma unroll
    for (int g = 0; g < 4; ++g) {
      const int v = vhi + 16 * g;
      float num = 0.f;
      #pragma unroll
      for (int ww = 0; ww < NW; ++ww) num += sm.epi.obuf[ww][n][v];
      out[((size_t)(b * CV + v)) * HWN + n0 + n] = num * inv + maskadd[b * CV + v];
    }
  }
}

// ---------------------------------------------------------------------------
extern "C" void kernel_launch(void* const* d_in, const int* in_sizes, int n_in,
                              void* d_out, int out_size, void* d_ws, size_t ws_size,
                              hipStream_t stream) {
  const float* keys  = (const float*)d_in[0];
  const float* vals  = (const float*)d_in[1];
  const float* query = (const float*)d_in[2];
  const float* disp  = (const float*)d_in[3];
  const int*   seq   = (const int*)d_in[4];
  float*       out   = (float*)d_out;

  _Float16*       kT   = (_Float16*)d_ws;
  unsigned short* vbf  = (unsigned short*)((char*)d_ws + KT_BYTES);
  float*          mask = (float*)((char*)d_ws + MASK_OFF);

  hipMemsetAsync(mask, 0, (size_t)NB * CV * 4, stream);
  prep_all<<<256 + NB * NS * CV, 512, 0, stream>>>(keys, vals, disp, seq, kT, vbf, mask);

  if (ws_size >= WS2) {
    float* onum   = (float*)((char*)d_ws + ONUM_OFF);
    float* odenom = (float*)((char*)d_ws + ODEN_OFF);
    attn_v4<<<NB * 64 * KS, 512, 0, stream>>>(kT, vbf, query, onum, odenom);
    finalize_k<<<NB * (HWN / 64), 256, 0, stream>>>(onum, odenom, mask, out);
  } else {
    attn_fast<<<NB * (HWN / TM), 512, 0, stream>>>(kT, vbf, query, mask, out);
  }
}

// Round 11
// 209.576 us; speedup vs baseline: 1.5579x; 1.0512x over previous
//
#include <hip/hip_runtime.h>
#include <hip/hip_bf16.h>
#include <stdint.h>

// Problem constants
#define NS   8
#define NB   2
#define CK   64
#define CV   64
#define HWN  4096
#define SHW  32768
#define RADIUS_ 0.1f
#define MASK_W  6.103515625e-6f   // 0.2 / 8 / 64 / 64

// Tiling
#define TM    32
#define NW    8
#define QS_STR 68           // fp32 Q stage stride
#define P_STR  40           // (fallback kernel) bf16 P row stride
#define P5_STR 32           // attn_v5 P row stride: 64 B rows, bank-optimal
#define SBIAS 24.0f
#define KS    4             // key splits

// Workspace layout
#define KT_ELEMS (NS * NB * CK * HWN)       // 4,194,304
#define KT_BYTES ((size_t)KT_ELEMS * 2)     // 8 MB fp16 transposed K
#define VB_BYTES ((size_t)KT_ELEMS * 2)     // 8 MB bf16 V
#define MASK_OFF (KT_BYTES + VB_BYTES)
#define WS_NEED  (MASK_OFF + (size_t)NB * CV * 4)
#define ONUM_OFF (MASK_OFF + 4096)
#define ONUM_BYTES ((size_t)KS * NB * HWN * CV * 4)          // 8.4 MB
#define ODEN_OFF (ONUM_OFF + ONUM_BYTES)
#define ODEN_BYTES ((size_t)KS * NB * HWN * 4)
#define WS2      (ODEN_OFF + ODEN_BYTES)                     // ~25.4 MB

typedef __bf16    bf16x8 __attribute__((ext_vector_type(8)));
typedef _Float16  f16x8  __attribute__((ext_vector_type(8)));
typedef float     f32x4  __attribute__((ext_vector_type(4)));
typedef unsigned short u16x8 __attribute__((ext_vector_type(8)));

__device__ __forceinline__ unsigned short f2bfu(float x) {
  __hip_bfloat16 h = __float2bfloat16(x);
  return __builtin_bit_cast(unsigned short, h);
}
__device__ __forceinline__ bf16x8 ld_bf8_lds(const unsigned short* p) {
  u16x8 u = *(const u16x8*)p;
  return __builtin_bit_cast(bf16x8, u);
}
// async global->LDS, 16B per lane; LDS dest = wave-uniform base + lane*16
__device__ __forceinline__ void load_lds16(const void* g, void* l) {
  __builtin_amdgcn_global_load_lds(
      (const __attribute__((address_space(1))) unsigned int*)g,
      (__attribute__((address_space(3))) unsigned int*)l, 16, 0, 0);
}

// ---------------------------------------------------------------------------
// Fused pre-pass:
//   blocks [0,256):    K fp32 [S,B,CK,HW] -> fp16 transposed kT[b][key][c]
//   blocks [256,1280): V fp32 -> bf16 (layout kept) + fused mask atomicAdd
// ---------------------------------------------------------------------------
#define PK_STR 72
__global__ __launch_bounds__(512) void prep_all(
    const float* __restrict__ keys, const float* __restrict__ vals,
    const float* __restrict__ disp, const int* __restrict__ seq,
    _Float16* __restrict__ kT, unsigned short* __restrict__ vbf,
    float* __restrict__ maskadd)
{
  const int t = threadIdx.x;
  const int blk = blockIdx.x;
  if (blk < 256) {
    __shared__ _Float16 lds[256 * PK_STR];
    const int chunk = blk & 15;
    const int s     = (blk >> 4) & 7;
    const int b     = blk >> 7;
    const int hw0   = chunk * 256;
    const int c_st  = t >> 3;
    const int msub  = (t & 7) * 8;

    const float* krow = keys + ((size_t)((s * NB + b) * CK + c_st)) * HWN + hw0;
    #pragma unroll
    for (int r = 0; r < 4; ++r) {
      const int m0 = msub + r * 64;
      f32x4 k0 = *(const f32x4*)(krow + m0);
      f32x4 k1 = *(const f32x4*)(krow + m0 + 4);
      #pragma unroll
      for (int j = 0; j < 4; ++j) {
        lds[(m0 + j)     * PK_STR + c_st] = (_Float16)k0[j];
        lds[(m0 + 4 + j) * PK_STR + c_st] = (_Float16)k1[j];
      }
    }
    __syncthreads();

    _Float16* kout = kT + ((size_t)(b * SHW + s * HWN + hw0)) * CK;
    const int mm = t >> 3, c0 = (t & 7) * 8;
    #pragma unroll
    for (int r2 = 0; r2 < 4; ++r2) {
      const int m = mm + r2 * 64;
      u16x8 v = *(const u16x8*)&lds[m * PK_STR + c0];
      *(u16x8*)(kout + (size_t)m * CK + c0) = v;
    }
  } else {
    // V path: one (s,b,c) row of 4096 elems per block
    const int r = blk - 256;           // 0..1023
    const int s = r >> 7;
    const int b = (r >> 6) & 1;
    const int c = r & 63;
    float j0 = (float)seq[(b * NS + s) * 2 + 0];
    float j1 = (float)seq[(b * NS + s) * 2 + 1];
    const float dist = sqrtf((j1 - 5.f) * (j1 - 5.f) + (j0 - 5.f) * (j0 - 5.f));

    const size_t i = (size_t)r * HWN + t * 8;
    const int hw = t * 8;
    f32x4 a  = *(const f32x4*)(vals + i);
    f32x4 bb = *(const f32x4*)(vals + i + 4);
    f32x4 d0 = *(const f32x4*)(disp + (size_t)b * HWN + hw);
    f32x4 d1 = *(const f32x4*)(disp + (size_t)b * HWN + hw + 4);
    u16x8 o;
    float acc = 0.f;
    #pragma unroll
    for (int j = 0; j < 4; ++j) {
      o[j]     = f2bfu(a[j]);
      o[4 + j] = f2bfu(bb[j]);
      if (fabsf(dist * d0[j]) > RADIUS_) acc += a[j];
      if (fabsf(dist * d1[j]) > RADIUS_) acc += bb[j];
    }
    *(u16x8*)(vbf + i) = o;

    #pragma unroll
    for (int m = 32; m >= 1; m >>= 1) acc += __shfl_xor(acc, m);
    __shared__ float red[8];
    if ((t & 63) == 0) red[t >> 6] = acc;
    __syncthreads();
    if (t == 0) {
      float s8 = 0.f;
      #pragma unroll
      for (int j = 0; j < 8; ++j) s8 += red[j];
      atomicAdd(&maskadd[b * CV + c], MASK_W * s8);
    }
  }
}

// ---------------------------------------------------------------------------
// attn_v5: TM=64, KS=4, XCD-L2 partition. BOTH K and V staged via
// double-buffered global_load_lds DMA (4 VMEM insts/wave-iter, all
// 8x128B-line coalesced). S^T MFMA, P b64 round-trip (P_STR=32, bank-optimal).
// LDS exactly 80 KB -> 2 blocks/CU.
// ---------------------------------------------------------------------------
struct __align__(16) Smem5 {
  union {
    struct {
      _Float16       kbuf[2][128 * 64];       // 32768 B [key][c ^ swz(key)]
      unsigned short vbuf[2][64 * 128];       // 32768 B [cv][chunk ^ (cv&7)]
      unsigned short p[NW][2][16 * P5_STR];   // 16384 B P round-trip
    } main;                                   // 81920 B total
    struct {
      float obuf[4][32][64];                  // 32768 B
      float dbuf[4][32];                      // 512 B
    } epi;
    float qs[64 * QS_STR];                    // 17408 B (prologue only)
  };
};

__global__ __launch_bounds__(512, 4) void attn_v5(
    const _Float16* __restrict__ kT,        // [B][SHW][CK] fp16
    const unsigned short* __restrict__ vbf, // [S,B,CV,HW] bf16
    const float* __restrict__ query,        // [B,CK,HW] fp32
    float* __restrict__ onum,               // [KS][B][HWN][CV]
    float* __restrict__ odenom)             // [KS][B][HWN]
{
  __shared__ Smem5 sm;
  const int t    = threadIdx.x;
  const int w    = t >> 6;
  const int lane = t & 63;
  const int quad = lane >> 4;
  const int l15  = lane & 15;
  const int kq   = w & 3;
  const int rg   = w >> 2;
  const int bidx = blockIdx.x;
  const int xcd  = bidx & 7;               // (ks<<1)|b -> one XCD per K/V slice
  const int b    = xcd & 1;
  const int ks   = xcd >> 1;
  const int tile = bidx >> 3;              // 0..63
  const int n0   = tile * 64;

  // --- Stage Q (64 rows) transposed fp32, then fp16 B-fragments ---
  {
    const int qc   = t >> 3;
    const int noff = (t & 7) * 8;
    const int slot = qc ^ ((t & 7) << 2);
    const float* qp = query + (size_t)(b * CK + qc) * HWN + n0 + noff;
    f32x4 q0 = *(const f32x4*)(qp);
    f32x4 q1 = *(const f32x4*)(qp + 4);
    #pragma unroll
    for (int j = 0; j < 4; ++j) {
      sm.qs[(noff + j)     * QS_STR + slot] = q0[j];
      sm.qs[(noff + 4 + j) * QS_STR + slot] = q1[j];
    }
  }
  __syncthreads();
  f16x8 qf[2][2];
  #pragma unroll
  for (int f = 0; f < 2; ++f) {
    const int n  = rg * 32 + f * 16 + l15;
    const int sw = ((n >> 3) & 7) << 2;
    const float* base = &sm.qs[n * QS_STR];
    #pragma unroll
    for (int h = 0; h < 2; ++h) {
      const int c0 = (h * 32 + quad * 8) ^ sw;
      f32x4 a  = *(const f32x4*)(base + c0);
      f32x4 bb = *(const f32x4*)(base + (c0 ^ 4));
      f16x8 q;
      #pragma unroll
      for (int j = 0; j < 4; ++j) { q[j] = (_Float16)a[j]; q[4 + j] = (_Float16)bb[j]; }
      qf[f][h] = q;
    }
  }
  __syncthreads();  // qs reads done; kbuf/vbuf region free for DMA

  f32x4 Of[2][4];
  f32x4 Ol[2];
  #pragma unroll
  for (int f = 0; f < 2; ++f) {
    #pragma unroll
    for (int cf = 0; cf < 4; ++cf) Of[f][cf] = (f32x4){0.f, 0.f, 0.f, 0.f};
    Ol[f] = (f32x4){0.f, 0.f, 0.f, 0.f};
  }
  bf16x8 vones;
  #pragma unroll
  for (int i = 0; i < 8; ++i)
    vones[i] = __builtin_bit_cast(__bf16, (unsigned short)0x3F80);

  // --- DMA addressing (2 K-insts + 2 V-insts per wave per tile) ---
  // K: inst covers 8 keys x full 128B row, gather-swizzled per lane.
  uint32_t ksrc_off[2];
  int      kldsoff[2];
  // V: inst covers 4 cv rows x 256B, chunk-swizzled per lane.
  uint32_t vsrc_off[2];   // in ushort units, relative to (frame/batch base + hw0)
  int      vldsoff[2];
  #pragma unroll
  for (int j = 0; j < 2; ++j) {
    const int inst = w * 2 + j;                 // 0..15
    const int kl   = inst * 8 + (lane >> 3);    // staged key 0..127
    const int cqs  = lane & 7;
    ksrc_off[j] = (uint32_t)(kl * 128 + ((cqs ^ (kl & 7)) * 16));
    kldsoff[j]  = inst * 1024;
    const int cv  = inst * 4 + (lane >> 4);     // staged cv row 0..63
    const int chs = (lane & 15) ^ (cv & 7);     // source chunk (16B = 8 bf16)
    vsrc_off[j] = (uint32_t)(cv * HWN + chs * 8);
    vldsoff[j]  = inst * 1024;
  }
  const char* kgbase = (const char*)(kT + (size_t)b * SHW * CK);
  const int   kbase0 = ks * (SHW / KS);

  // Prologue: DMA tile 0 into buf 0
  {
    const char* kg = kgbase + (size_t)kbase0 * 128;
    load_lds16(kg + ksrc_off[0], (char*)sm.main.kbuf[0] + kldsoff[0]);
    load_lds16(kg + ksrc_off[1], (char*)sm.main.kbuf[0] + kldsoff[1]);
    const int sfrm0 = kbase0 >> 12;
    const unsigned short* vg =
        vbf + (size_t)((sfrm0 * NB + b) * CV) * HWN + (kbase0 & 4095);
    load_lds16(vg + vsrc_off[0], (char*)sm.main.vbuf[0] + vldsoff[0]);
    load_lds16(vg + vsrc_off[1], (char*)sm.main.vbuf[0] + vldsoff[1]);
  }

  for (int it = 0; it < 64; ++it) {
    const int cur  = it & 1;
    const int key0 = kbase0 + it * 128;

    __syncthreads();  // tile `it` landed (drains vmcnt); buf[cur^1] free

    // --- prefetch tile it+1 into the other buffer (hidden by this compute) ---
    if (it < 63) {
      const int keyn = key0 + 128;
      const char* kg = kgbase + (size_t)keyn * 128;
      load_lds16(kg + ksrc_off[0], (char*)sm.main.kbuf[cur ^ 1] + kldsoff[0]);
      load_lds16(kg + ksrc_off[1], (char*)sm.main.kbuf[cur ^ 1] + kldsoff[1]);
      const int sfrmn = keyn >> 12;
      const unsigned short* vg =
          vbf + (size_t)((sfrmn * NB + b) * CV) * HWN + (keyn & 4095);
      load_lds16(vg + vsrc_off[0], (char*)sm.main.vbuf[cur ^ 1] + vldsoff[0]);
      load_lds16(vg + vsrc_off[1], (char*)sm.main.vbuf[cur ^ 1] + vldsoff[1]);
    }

    // --- K A-fragments from LDS (swizzled) ---
    f16x8 kf[2][2];
    #pragma unroll
    for (int g = 0; g < 2; ++g) {
      const int kl  = kq * 32 + g * 16 + l15;
      const int swz = kl & 7;
      const _Float16* kb = &sm.main.kbuf[cur][kl * 64];
      #pragma unroll
      for (int h = 0; h < 2; ++h) {
        const int slot = (h * 4 + quad) ^ swz;
        kf[g][h] = *(const f16x8*)(kb + slot * 8);
      }
    }

    // --- V B-fragments from LDS (swizzled): row cv, chunk kq*4+quad ---
    bf16x8 vf[4];
    #pragma unroll
    for (int cf = 0; cf < 4; ++cf) {
      const int cv = cf * 16 + l15;
      const int c  = (kq * 4 + quad) ^ (cv & 7);
      vf[cf] = ld_bf8_lds(&sm.main.vbuf[cur][cv * 128 + c * 8]);
    }

    // --- S^T = K @ Q^T: D rows = key (quad*4+r), cols = qrow (l15) ---
    f32x4 sf[2][2];
    #pragma unroll
    for (int g = 0; g < 2; ++g)
      #pragma unroll
      for (int f = 0; f < 2; ++f) {
        f32x4 acc = (f32x4){0.f, 0.f, 0.f, 0.f};
        acc = __builtin_amdgcn_mfma_f32_16x16x32_f16(kf[g][0], qf[f][0], acc, 0, 0, 0);
        acc = __builtin_amdgcn_mfma_f32_16x16x32_f16(kf[g][1], qf[f][1], acc, 0, 0, 0);
        sf[g][f] = acc;
      }

    // --- P = exp(S - SBIAS), truncation-packed -> b64 LDS writes ---
    #pragma unroll
    for (int g = 0; g < 2; ++g)
      #pragma unroll
      for (int f = 0; f < 2; ++f) {
        float e0 = __expf(sf[g][f][0] - SBIAS);
        float e1 = __expf(sf[g][f][1] - SBIAS);
        float e2 = __expf(sf[g][f][2] - SBIAS);
        float e3 = __expf(sf[g][f][3] - SBIAS);
        uint2 pk;
        pk.x = (__builtin_bit_cast(unsigned, e0) >> 16) |
               (__builtin_bit_cast(unsigned, e1) & 0xFFFF0000u);
        pk.y = (__builtin_bit_cast(unsigned, e2) >> 16) |
               (__builtin_bit_cast(unsigned, e3) & 0xFFFF0000u);
        // row = l15 (qrow, 64B rows), cols = g*16 + quad*4 .. +3 (keys)
        *(uint2*)((char*)&sm.main.p[w][f][0] + l15 * 64 + g * 32 + quad * 8) = pk;
      }
    asm volatile("s_waitcnt lgkmcnt(0)" ::: "memory");  // in-wave write->read
    bf16x8 pf[2];
    #pragma unroll
    for (int f = 0; f < 2; ++f)
      pf[f] = ld_bf8_lds(&sm.main.p[w][f][l15 * P5_STR + quad * 8]);

    // --- O += P @ V, l += P @ 1 ---
    #pragma unroll
    for (int f = 0; f < 2; ++f) {
      #pragma unroll
      for (int cf = 0; cf < 4; ++cf)
        Of[f][cf] = __builtin_amdgcn_mfma_f32_16x16x32_bf16(pf[f], vf[cf], Of[f][cf], 0, 0, 0);
      Ol[f] = __builtin_amdgcn_mfma_f32_16x16x32_bf16(pf[f], vones, Ol[f], 0, 0, 0);
    }
  }

  __syncthreads();  // all waves done with main region before epi alias

  // --- Epilogue: reduce 4 kq waves per rg phase, store partials ---
  #pragma unroll
  for (int phase = 0; phase < 2; ++phase) {
    if (rg == phase) {
      #pragma unroll
      for (int f = 0; f < 2; ++f)
        #pragma unroll
        for (int r = 0; r < 4; ++r) {
          const int row = f * 16 + quad * 4 + r;
          if (l15 == 0) sm.epi.dbuf[kq][row] = Ol[f][r];
          #pragma unroll
          for (int cf = 0; cf < 4; ++cf)
            sm.epi.obuf[kq][row][cf * 16 + l15] = Of[f][cf][r];
        }
    }
    __syncthreads();
    {
      const int row = t >> 4;
      const int v4  = (t & 15) * 4;
      f32x4 acc = *(const f32x4*)&sm.epi.obuf[0][row][v4];
      #pragma unroll
      for (int q = 1; q < 4; ++q)
        acc += *(const f32x4*)&sm.epi.obuf[q][row][v4];
      *(f32x4*)&onum[((size_t)(ks * NB + b) * HWN + n0 + phase * 32 + row) * CV + v4] = acc;
      if (t < 32) {
        float d = sm.epi.dbuf[0][t] + sm.epi.dbuf[1][t] +
                  sm.epi.dbuf[2][t] + sm.epi.dbuf[3][t];
        odenom[(size_t)(ks * NB + b) * HWN + n0 + phase * 32 + t] = d;
      }
    }
    __syncthreads();
  }
}

// ---------------------------------------------------------------------------
// Finalize: out[b][v][hw] = sum_ks onum / sum_ks odenom + mask
// ---------------------------------------------------------------------------
__global__ __launch_bounds__(256) void finalize_k(
    const float* __restrict__ onum, const float* __restrict__ odenom,
    const float* __restrict__ maskadd, float* __restrict__ out)
{
  __shared__ float tile[64][68];
  __shared__ float dinv[64];
  __shared__ float ml[64];
  const int t   = threadIdx.x;
  const int b   = blockIdx.x >> 6;
  const int hw0 = (blockIdx.x & 63) * 64;

  #pragma unroll
  for (int pass = 0; pass < 4; ++pass) {
    const int row = pass * 16 + (t >> 4);
    const int v4  = (t & 15) * 4;
    f32x4 acc = (f32x4){0.f, 0.f, 0.f, 0.f};
    #pragma unroll
    for (int ks = 0; ks < KS; ++ks)
      acc += *(const f32x4*)&onum[((size_t)(ks * NB + b) * HWN + hw0 + row) * CV + v4];
    *(f32x4*)&tile[row][v4] = acc;
  }
  if (t < 64) {
    float d = 0.f;
    #pragma unroll
    for (int ks = 0; ks < KS; ++ks)
      d += odenom[(size_t)(ks * NB + b) * HWN + hw0 + t];
    dinv[t] = 1.f / fmaxf(d, 1e-30f);
  }
  if (t >= 64 && t < 128) ml[t - 64] = maskadd[b * CV + (t - 64)];
  __syncthreads();

  #pragma unroll
  for (int pass = 0; pass < 4; ++pass) {
    const int v   = pass * 16 + (t >> 4);
    const int hw4 = (t & 15) * 4;
    f32x4 o;
    #pragma unroll
    for (int j = 0; j < 4; ++j)
      o[j] = tile[hw4 + j][v] * dinv[hw4 + j] + ml[v];
    *(f32x4*)&out[((size_t)(b * CV + v)) * HWN + hw0 + hw4] = o;
  }
}

// ---------------------------------------------------------------------------
// Round-6 attention (fallback, small ws)
// ---------------------------------------------------------------------------
struct __align__(16) SmemF {
  union {
    float qs[TM * QS_STR];
    unsigned short p[NW][2][16 * P_STR];
    struct {
      float obuf[NW][TM][CV];
      float lbuf[NW][TM];
    } epi;
  };
};

__global__ __launch_bounds__(512) void attn_fast(
    const _Float16* __restrict__ kT, const unsigned short* __restrict__ vbf,
    const float* __restrict__ query, const float* __restrict__ maskadd,
    float* __restrict__ out)
{
  __shared__ SmemF sm;
  const int t    = threadIdx.x;
  const int w    = t >> 6;
  const int lane = t & 63;
  const int quad = lane >> 4;
  const int l15  = lane & 15;
  const int bidx = blockIdx.x;
  const int b    = bidx & 1;
  const int n0   = ((bidx >> 1) & 127) * TM;

  if (t < 256) {
    const int qc   = t >> 2;
    const int noff = (t & 3) * 8;
    const int slot = qc ^ ((t & 3) << 2);
    const float* qp = query + (size_t)(b * CK + qc) * HWN + n0 + noff;
    f32x4 q0 = *(const f32x4*)(qp);
    f32x4 q1 = *(const f32x4*)(qp + 4);
    #pragma unroll
    for (int j = 0; j < 4; ++j) {
      sm.qs[(noff + j)     * QS_STR + slot] = q0[j];
      sm.qs[(noff + 4 + j) * QS_STR + slot] = q1[j];
    }
  }
  __syncthreads();
  f16x8 qf[2][2];
  #pragma unroll
  for (int f = 0; f < 2; ++f) {
    const int n  = f * 16 + l15;
    const int sw = ((n >> 3) & 7) << 2;
    const float* base = &sm.qs[n * QS_STR];
    #pragma unroll
    for (int h = 0; h < 2; ++h) {
      const int c0 = (h * 32 + quad * 8) ^ sw;
      f32x4 a  = *(const f32x4*)(base + c0);
      f32x4 bb = *(const f32x4*)(base + (c0 ^ 4));
      f16x8 q;
      #pragma unroll
      for (int j = 0; j < 4; ++j) { q[j] = (_Float16)a[j]; q[4 + j] = (_Float16)bb[j]; }
      qf[f][h] = q;
    }
  }
  __syncthreads();

  f32x4 Of[2][4];
  f32x4 Ol[2];
  #pragma unroll
  for (int f = 0; f < 2; ++f) {
    #pragma unroll
    for (int cf = 0; cf < 4; ++cf) Of[f][cf] = (f32x4){0.f, 0.f, 0.f, 0.f};
    Ol[f] = (f32x4){0.f, 0.f, 0.f, 0.f};
  }
  bf16x8 vones;
  #pragma unroll
  for (int i = 0; i < 8; ++i)
    vones[i] = __builtin_bit_cast(__bf16, (unsigned short)0x3F80);

  const _Float16* kbase = kT + (size_t)b * SHW * CK;

  for (int it = 0; it < SHW / 256; ++it) {
    const int key0 = it * 256 + w * 32;
    f16x8 kf[2][2];
    #pragma unroll
    for (int g = 0; g < 2; ++g)
      #pragma unroll
      for (int h = 0; h < 2; ++h)
        kf[g][h] = *(const f16x8*)(kbase +
            (size_t)(key0 + g * 16 + l15) * CK + h * 32 + quad * 8);

    const int s   = it >> 4;
    const int hwv = (it & 15) * 256 + w * 32 + quad * 8;
    bf16x8 vf[4];
    #pragma unroll
    for (int cf = 0; cf < 4; ++cf)
      vf[cf] = ld_bf8_lds(vbf +
          ((size_t)((s * NB + b) * CV + cf * 16 + l15)) * HWN + hwv);

    f32x4 sfv[2][2];
    #pragma unroll
    for (int f = 0; f < 2; ++f)
      #pragma unroll
      for (int g = 0; g < 2; ++g) {
        f32x4 acc = (f32x4){0.f, 0.f, 0.f, 0.f};
        acc = __builtin_amdgcn_mfma_f32_16x16x32_f16(qf[f][0], kf[g][0], acc, 0, 0, 0);
        acc = __builtin_amdgcn_mfma_f32_16x16x32_f16(qf[f][1], kf[g][1], acc, 0, 0, 0);
        sfv[f][g] = acc;
      }

    #pragma unroll
    for (int f = 0; f < 2; ++f)
      #pragma unroll
      for (int g = 0; g < 2; ++g)
        #pragma unroll
        for (int r = 0; r < 4; ++r)
          sfv[f][g][r] = __expf(sfv[f][g][r] - SBIAS);

    #pragma unroll
    for (int f = 0; f < 2; ++f)
      #pragma unroll
      for (int g = 0; g < 2; ++g)
        #pragma unroll
        for (int r = 0; r < 4; ++r)
          sm.p[w][f][(quad * 4 + r) * P_STR + g * 16 + l15] = f2bfu(sfv[f][g][r]);
    asm volatile("s_waitcnt lgkmcnt(0)" ::: "memory");
    bf16x8 pf[2];
    #pragma unroll
    for (int f = 0; f < 2; ++f)
      pf[f] = ld_bf8_lds(&sm.p[w][f][l15 * P_STR + quad * 8]);

    #pragma unroll
    for (int f = 0; f < 2; ++f) {
      #pragma unroll
      for (int cf = 0; cf < 4; ++cf)
        Of[f][cf] = __builtin_amdgcn_mfma_f32_16x16x32_bf16(pf[f], vf[cf], Of[f][cf], 0, 0, 0);
      Ol[f] = __builtin_amdgcn_mfma_f32_16x16x32_bf16(pf[f], vones, Ol[f], 0, 0, 0);
    }
  }

  __syncthreads();
  #pragma unroll
  for (int f = 0; f < 2; ++f)
    #pragma unroll
    for (int r = 0; r < 4; ++r) {
      const int row = f * 16 + quad * 4 + r;
      if (l15 == 0) sm.epi.lbuf[w][row] = Ol[f][r];
      #pragma unroll
      for (int cf = 0; cf < 4; ++cf)
        sm.epi.obuf[w][row][cf * 16 + l15] = Of[f][cf][r];
    }
  __syncthreads();
  {
    const int n   = t & 31;
    const int vhi = t >> 5;
    float denom = 0.f;
    #pragma unroll
    for (int ww = 0; ww < NW; ++ww) denom += sm.epi.lbuf[ww][n];
    const float inv = 1.f / fmaxf(denom, 1e-30f);
    #pragma unroll
    for (int g = 0; g < 4; ++g) {
      const int v = vhi + 16 * g;
      float num = 0.f;
      #pragma unroll
      for (int ww = 0; ww < NW; ++ww) num += sm.epi.obuf[ww][n][v];
      out[((size_t)(b * CV + v)) * HWN + n0 + n] = num * inv + maskadd[b * CV + v];
    }
  }
}

// ---------------------------------------------------------------------------
extern "C" void kernel_launch(void* const* d_in, const int* in_sizes, int n_in,
                              void* d_out, int out_size, void* d_ws, size_t ws_size,
                              hipStream_t stream) {
  const float* keys  = (const float*)d_in[0];
  const float* vals  = (const float*)d_in[1];
  const float* query = (const float*)d_in[2];
  const float* disp  = (const float*)d_in[3];
  const int*   seq   = (const int*)d_in[4];
  float*       out   = (float*)d_out;

  _Float16*       kT   = (_Float16*)d_ws;
  unsigned short* vbf  = (unsigned short*)((char*)d_ws + KT_BYTES);
  float*          mask = (float*)((char*)d_ws + MASK_OFF);

  hipMemsetAsync(mask, 0, (size_t)NB * CV * 4, stream);
  prep_all<<<256 + NB * NS * CV, 512, 0, stream>>>(keys, vals, disp, seq, kT, vbf, mask);

  if (ws_size >= WS2) {
    float* onum   = (float*)((char*)d_ws + ONUM_OFF);
    float* odenom = (float*)((char*)d_ws + ODEN_OFF);
    attn_v5<<<NB * 64 * KS, 512, 0, stream>>>(kT, vbf, query, onum, odenom);
    finalize_k<<<NB * (HWN / 64), 256, 0, stream>>>(onum, odenom, mask, out);
  } else {
    attn_fast<<<NB * (HWN / TM), 512, 0, stream>>>(kT, vbf, query, mask, out);
  }
}

// Round 12
// 181.035 us; speedup vs baseline: 1.8036x; 1.1577x over previous
//
#include <hip/hip_runtime.h>
#include <hip/hip_bf16.h>
#include <stdint.h>

// Problem constants
#define NS   8
#define NB   2
#define CK   64
#define CV   64
#define HWN  4096
#define SHW  32768
#define RADIUS_ 0.1f
#define MASK_W  6.103515625e-6f   // 0.2 / 8 / 64 / 64

// Tiling
#define TM    32
#define NW    8
#define QS_STR 68           // fp32 Q stage stride
#define P_STR  40           // bf16 P row stride (80 B rows: l15*20 mod 32 spans all 8 bank groups)
#define SBIAS 24.0f
#define KS    4             // key splits

// Workspace layout
#define KT_ELEMS (NS * NB * CK * HWN)       // 4,194,304
#define KT_BYTES ((size_t)KT_ELEMS * 2)     // 8 MB fp16 transposed K
#define VB_BYTES ((size_t)KT_ELEMS * 2)     // 8 MB bf16 V
#define MASK_OFF (KT_BYTES + VB_BYTES)
#define WS_NEED  (MASK_OFF + (size_t)NB * CV * 4)
#define ONUM_OFF (MASK_OFF + 4096)
#define ONUM_BYTES ((size_t)KS * NB * HWN * CV * 4)          // 8.4 MB
#define ODEN_OFF (ONUM_OFF + ONUM_BYTES)
#define ODEN_BYTES ((size_t)KS * NB * HWN * 4)
#define WS2      (ODEN_OFF + ODEN_BYTES)                     // ~25.4 MB

typedef __bf16    bf16x8 __attribute__((ext_vector_type(8)));
typedef _Float16  f16x8  __attribute__((ext_vector_type(8)));
typedef float     f32x4  __attribute__((ext_vector_type(4)));
typedef unsigned short u16x8 __attribute__((ext_vector_type(8)));

__device__ __forceinline__ unsigned short f2bfu(float x) {
  __hip_bfloat16 h = __float2bfloat16(x);
  return __builtin_bit_cast(unsigned short, h);
}
__device__ __forceinline__ bf16x8 ld_bf8_lds(const unsigned short* p) {
  u16x8 u = *(const u16x8*)p;
  return __builtin_bit_cast(bf16x8, u);
}
// async global->LDS, 16B per lane; LDS dest = wave-uniform base + lane*16
__device__ __forceinline__ void load_lds16(const void* g, void* l) {
  __builtin_amdgcn_global_load_lds(
      (const __attribute__((address_space(1))) unsigned int*)g,
      (__attribute__((address_space(3))) unsigned int*)l, 16, 0, 0);
}

// ---------------------------------------------------------------------------
// Fused pre-pass:
//   blocks [0,256):    K fp32 [S,B,CK,HW] -> fp16 transposed kT[b][key][c]
//   blocks [256,1280): V fp32 -> bf16 (layout kept) + fused mask atomicAdd
// ---------------------------------------------------------------------------
#define PK_STR 72
__global__ __launch_bounds__(512) void prep_all(
    const float* __restrict__ keys, const float* __restrict__ vals,
    const float* __restrict__ disp, const int* __restrict__ seq,
    _Float16* __restrict__ kT, unsigned short* __restrict__ vbf,
    float* __restrict__ maskadd)
{
  const int t = threadIdx.x;
  const int blk = blockIdx.x;
  if (blk < 256) {
    __shared__ _Float16 lds[256 * PK_STR];
    const int chunk = blk & 15;
    const int s     = (blk >> 4) & 7;
    const int b     = blk >> 7;
    const int hw0   = chunk * 256;
    const int c_st  = t >> 3;
    const int msub  = (t & 7) * 8;

    const float* krow = keys + ((size_t)((s * NB + b) * CK + c_st)) * HWN + hw0;
    #pragma unroll
    for (int r = 0; r < 4; ++r) {
      const int m0 = msub + r * 64;
      f32x4 k0 = *(const f32x4*)(krow + m0);
      f32x4 k1 = *(const f32x4*)(krow + m0 + 4);
      #pragma unroll
      for (int j = 0; j < 4; ++j) {
        lds[(m0 + j)     * PK_STR + c_st] = (_Float16)k0[j];
        lds[(m0 + 4 + j) * PK_STR + c_st] = (_Float16)k1[j];
      }
    }
    __syncthreads();

    _Float16* kout = kT + ((size_t)(b * SHW + s * HWN + hw0)) * CK;
    const int mm = t >> 3, c0 = (t & 7) * 8;
    #pragma unroll
    for (int r2 = 0; r2 < 4; ++r2) {
      const int m = mm + r2 * 64;
      u16x8 v = *(const u16x8*)&lds[m * PK_STR + c0];
      *(u16x8*)(kout + (size_t)m * CK + c0) = v;
    }
  } else {
    // V path: one (s,b,c) row of 4096 elems per block
    const int r = blk - 256;           // 0..1023
    const int s = r >> 7;
    const int b = (r >> 6) & 1;
    const int c = r & 63;
    float j0 = (float)seq[(b * NS + s) * 2 + 0];
    float j1 = (float)seq[(b * NS + s) * 2 + 1];
    const float dist = sqrtf((j1 - 5.f) * (j1 - 5.f) + (j0 - 5.f) * (j0 - 5.f));

    const size_t i = (size_t)r * HWN + t * 8;
    const int hw = t * 8;
    f32x4 a  = *(const f32x4*)(vals + i);
    f32x4 bb = *(const f32x4*)(vals + i + 4);
    f32x4 d0 = *(const f32x4*)(disp + (size_t)b * HWN + hw);
    f32x4 d1 = *(const f32x4*)(disp + (size_t)b * HWN + hw + 4);
    u16x8 o;
    float acc = 0.f;
    #pragma unroll
    for (int j = 0; j < 4; ++j) {
      o[j]     = f2bfu(a[j]);
      o[4 + j] = f2bfu(bb[j]);
      if (fabsf(dist * d0[j]) > RADIUS_) acc += a[j];
      if (fabsf(dist * d1[j]) > RADIUS_) acc += bb[j];
    }
    *(u16x8*)(vbf + i) = o;

    #pragma unroll
    for (int m = 32; m >= 1; m >>= 1) acc += __shfl_xor(acc, m);
    __shared__ float red[8];
    if ((t & 63) == 0) red[t >> 6] = acc;
    __syncthreads();
    if (t == 0) {
      float s8 = 0.f;
      #pragma unroll
      for (int j = 0; j < 8; ++j) s8 += red[j];
      atomicAdd(&maskadd[b * CV + c], MASK_W * s8);
    }
  }
}

// ---------------------------------------------------------------------------
// attn_v6: TM=64, KS=4, XCD-L2 partition. K and V staged via double-buffered
// global_load_lds DMA (4 VMEM insts/wave-iter). S^T MFMA.
// P round-trip: f-sequential per-wave buffer, 80 B rows (conflict-free:
// l15*20 mod 32 spans all 8 bank groups). Main LDS = 75776 B -> 2 blocks/CU.
// ---------------------------------------------------------------------------
struct __align__(16) Smem6 {
  union {
    struct {
      _Float16       kbuf[2][128 * 64];       // 32768 B [key][c ^ swz(key)]
      unsigned short vbuf[2][64 * 128];       // 32768 B [cv][chunk ^ (cv&7)]
      unsigned short p[NW][16 * P_STR];       // 10240 B P round-trip (f-seq)
    } main;                                   // 75776 B total
    struct {
      float obuf[4][32][64];                  // 32768 B
      float dbuf[4][32];                      // 512 B
    } epi;
    float qs[64 * QS_STR];                    // 17408 B (prologue only)
  };
};

__global__ __launch_bounds__(512, 4) void attn_v6(
    const _Float16* __restrict__ kT,        // [B][SHW][CK] fp16
    const unsigned short* __restrict__ vbf, // [S,B,CV,HW] bf16
    const float* __restrict__ query,        // [B,CK,HW] fp32
    float* __restrict__ onum,               // [KS][B][HWN][CV]
    float* __restrict__ odenom)             // [KS][B][HWN]
{
  __shared__ Smem6 sm;
  const int t    = threadIdx.x;
  const int w    = t >> 6;
  const int lane = t & 63;
  const int quad = lane >> 4;
  const int l15  = lane & 15;
  const int kq   = w & 3;
  const int rg   = w >> 2;
  const int bidx = blockIdx.x;
  const int xcd  = bidx & 7;               // (ks<<1)|b -> one XCD per K/V slice
  const int b    = xcd & 1;
  const int ks   = xcd >> 1;
  const int tile = bidx >> 3;              // 0..63
  const int n0   = tile * 64;

  // --- Stage Q (64 rows) transposed fp32, then fp16 B-fragments ---
  {
    const int qc   = t >> 3;
    const int noff = (t & 7) * 8;
    const int slot = qc ^ ((t & 7) << 2);
    const float* qp = query + (size_t)(b * CK + qc) * HWN + n0 + noff;
    f32x4 q0 = *(const f32x4*)(qp);
    f32x4 q1 = *(const f32x4*)(qp + 4);
    #pragma unroll
    for (int j = 0; j < 4; ++j) {
      sm.qs[(noff + j)     * QS_STR + slot] = q0[j];
      sm.qs[(noff + 4 + j) * QS_STR + slot] = q1[j];
    }
  }
  __syncthreads();
  f16x8 qf[2][2];
  #pragma unroll
  for (int f = 0; f < 2; ++f) {
    const int n  = rg * 32 + f * 16 + l15;
    const int sw = ((n >> 3) & 7) << 2;
    const float* base = &sm.qs[n * QS_STR];
    #pragma unroll
    for (int h = 0; h < 2; ++h) {
      const int c0 = (h * 32 + quad * 8) ^ sw;
      f32x4 a  = *(const f32x4*)(base + c0);
      f32x4 bb = *(const f32x4*)(base + (c0 ^ 4));
      f16x8 q;
      #pragma unroll
      for (int j = 0; j < 4; ++j) { q[j] = (_Float16)a[j]; q[4 + j] = (_Float16)bb[j]; }
      qf[f][h] = q;
    }
  }
  __syncthreads();  // qs reads done; kbuf/vbuf region free for DMA

  f32x4 Of[2][4];
  f32x4 Ol[2];
  #pragma unroll
  for (int f = 0; f < 2; ++f) {
    #pragma unroll
    for (int cf = 0; cf < 4; ++cf) Of[f][cf] = (f32x4){0.f, 0.f, 0.f, 0.f};
    Ol[f] = (f32x4){0.f, 0.f, 0.f, 0.f};
  }
  bf16x8 vones;
  #pragma unroll
  for (int i = 0; i < 8; ++i)
    vones[i] = __builtin_bit_cast(__bf16, (unsigned short)0x3F80);

  // --- DMA addressing (2 K-insts + 2 V-insts per wave per tile) ---
  uint32_t ksrc_off[2];
  int      kldsoff[2];
  uint32_t vsrc_off[2];   // ushort units, relative to frame/batch base + hw0
  int      vldsoff[2];
  #pragma unroll
  for (int j = 0; j < 2; ++j) {
    const int inst = w * 2 + j;                 // 0..15
    const int kl   = inst * 8 + (lane >> 3);    // staged key 0..127
    const int cqs  = lane & 7;
    ksrc_off[j] = (uint32_t)(kl * 128 + ((cqs ^ (kl & 7)) * 16));
    kldsoff[j]  = inst * 1024;
    const int cv  = inst * 4 + (lane >> 4);     // staged cv row 0..63
    const int chs = (lane & 15) ^ (cv & 7);     // source chunk (16B = 8 bf16)
    vsrc_off[j] = (uint32_t)(cv * HWN + chs * 8);
    vldsoff[j]  = inst * 1024;
  }
  const char* kgbase = (const char*)(kT + (size_t)b * SHW * CK);
  const int   kbase0 = ks * (SHW / KS);

  // Prologue: DMA tile 0 into buf 0
  {
    const char* kg = kgbase + (size_t)kbase0 * 128;
    load_lds16(kg + ksrc_off[0], (char*)sm.main.kbuf[0] + kldsoff[0]);
    load_lds16(kg + ksrc_off[1], (char*)sm.main.kbuf[0] + kldsoff[1]);
    const int sfrm0 = kbase0 >> 12;
    const unsigned short* vg =
        vbf + (size_t)((sfrm0 * NB + b) * CV) * HWN + (kbase0 & 4095);
    load_lds16(vg + vsrc_off[0], (char*)sm.main.vbuf[0] + vldsoff[0]);
    load_lds16(vg + vsrc_off[1], (char*)sm.main.vbuf[0] + vldsoff[1]);
  }

  for (int it = 0; it < 64; ++it) {
    const int cur  = it & 1;
    const int key0 = kbase0 + it * 128;

    __syncthreads();  // tile `it` landed (drains vmcnt); buf[cur^1] free

    // --- prefetch tile it+1 into the other buffer ---
    if (it < 63) {
      const int keyn = key0 + 128;
      const char* kg = kgbase + (size_t)keyn * 128;
      load_lds16(kg + ksrc_off[0], (char*)sm.main.kbuf[cur ^ 1] + kldsoff[0]);
      load_lds16(kg + ksrc_off[1], (char*)sm.main.kbuf[cur ^ 1] + kldsoff[1]);
      const int sfrmn = keyn >> 12;
      const unsigned short* vg =
          vbf + (size_t)((sfrmn * NB + b) * CV) * HWN + (keyn & 4095);
      load_lds16(vg + vsrc_off[0], (char*)sm.main.vbuf[cur ^ 1] + vldsoff[0]);
      load_lds16(vg + vsrc_off[1], (char*)sm.main.vbuf[cur ^ 1] + vldsoff[1]);
    }

    // --- K A-fragments from LDS (swizzled) ---
    f16x8 kf[2][2];
    #pragma unroll
    for (int g = 0; g < 2; ++g) {
      const int kl  = kq * 32 + g * 16 + l15;
      const int swz = kl & 7;
      const _Float16* kb = &sm.main.kbuf[cur][kl * 64];
      #pragma unroll
      for (int h = 0; h < 2; ++h) {
        const int slot = (h * 4 + quad) ^ swz;
        kf[g][h] = *(const f16x8*)(kb + slot * 8);
      }
    }

    // --- V B-fragments from LDS (swizzled): row cv, chunk kq*4+quad ---
    bf16x8 vf[4];
    #pragma unroll
    for (int cf = 0; cf < 4; ++cf) {
      const int cv = cf * 16 + l15;
      const int c  = (kq * 4 + quad) ^ (cv & 7);
      vf[cf] = ld_bf8_lds(&sm.main.vbuf[cur][cv * 128 + c * 8]);
    }

    // --- S^T = K @ Q^T: D rows = key (quad*4+r), cols = qrow (l15) ---
    f32x4 sf[2][2];
    #pragma unroll
    for (int g = 0; g < 2; ++g)
      #pragma unroll
      for (int f = 0; f < 2; ++f) {
        f32x4 acc = (f32x4){0.f, 0.f, 0.f, 0.f};
        acc = __builtin_amdgcn_mfma_f32_16x16x32_f16(kf[g][0], qf[f][0], acc, 0, 0, 0);
        acc = __builtin_amdgcn_mfma_f32_16x16x32_f16(kf[g][1], qf[f][1], acc, 0, 0, 0);
        sf[g][f] = acc;
      }

    // --- P = exp(S-SBIAS), truncation-packed; f-SEQUENTIAL round-trip
    //     through the per-wave 80B-row buffer (conflict-free banks) ---
    #pragma unroll
    for (int f = 0; f < 2; ++f) {
      #pragma unroll
      for (int g = 0; g < 2; ++g) {
        float e0 = __expf(sf[g][f][0] - SBIAS);
        float e1 = __expf(sf[g][f][1] - SBIAS);
        float e2 = __expf(sf[g][f][2] - SBIAS);
        float e3 = __expf(sf[g][f][3] - SBIAS);
        uint2 pk;
        pk.x = (__builtin_bit_cast(unsigned, e0) >> 16) |
               (__builtin_bit_cast(unsigned, e1) & 0xFFFF0000u);
        pk.y = (__builtin_bit_cast(unsigned, e2) >> 16) |
               (__builtin_bit_cast(unsigned, e3) & 0xFFFF0000u);
        // row = l15 (80 B rows), cols = g*16 + quad*4 .. +3 (keys)
        *(uint2*)((char*)&sm.main.p[w][0] + l15 * 80 + g * 32 + quad * 8) = pk;
      }
      asm volatile("s_waitcnt lgkmcnt(0)" ::: "memory");  // in-wave write->read
      bf16x8 pf = ld_bf8_lds(&sm.main.p[w][l15 * P_STR + quad * 8]);

      #pragma unroll
      for (int cf = 0; cf < 4; ++cf)
        Of[f][cf] = __builtin_amdgcn_mfma_f32_16x16x32_bf16(pf, vf[cf], Of[f][cf], 0, 0, 0);
      Ol[f] = __builtin_amdgcn_mfma_f32_16x16x32_bf16(pf, vones, Ol[f], 0, 0, 0);
    }
  }

  __syncthreads();  // all waves done with main region before epi alias

  // --- Epilogue: reduce 4 kq waves per rg phase, store partials ---
  #pragma unroll
  for (int phase = 0; phase < 2; ++phase) {
    if (rg == phase) {
      #pragma unroll
      for (int f = 0; f < 2; ++f)
        #pragma unroll
        for (int r = 0; r < 4; ++r) {
          const int row = f * 16 + quad * 4 + r;
          if (l15 == 0) sm.epi.dbuf[kq][row] = Ol[f][r];
          #pragma unroll
          for (int cf = 0; cf < 4; ++cf)
            sm.epi.obuf[kq][row][cf * 16 + l15] = Of[f][cf][r];
        }
    }
    __syncthreads();
    {
      const int row = t >> 4;
      const int v4  = (t & 15) * 4;
      f32x4 acc = *(const f32x4*)&sm.epi.obuf[0][row][v4];
      #pragma unroll
      for (int q = 1; q < 4; ++q)
        acc += *(const f32x4*)&sm.epi.obuf[q][row][v4];
      *(f32x4*)&onum[((size_t)(ks * NB + b) * HWN + n0 + phase * 32 + row) * CV + v4] = acc;
      if (t < 32) {
        float d = sm.epi.dbuf[0][t] + sm.epi.dbuf[1][t] +
                  sm.epi.dbuf[2][t] + sm.epi.dbuf[3][t];
        odenom[(size_t)(ks * NB + b) * HWN + n0 + phase * 32 + t] = d;
      }
    }
    __syncthreads();
  }
}

// ---------------------------------------------------------------------------
// Finalize: out[b][v][hw] = sum_ks onum / sum_ks odenom + mask
// ---------------------------------------------------------------------------
__global__ __launch_bounds__(256) void finalize_k(
    const float* __restrict__ onum, const float* __restrict__ odenom,
    const float* __restrict__ maskadd, float* __restrict__ out)
{
  __shared__ float tile[64][68];
  __shared__ float dinv[64];
  __shared__ float ml[64];
  const int t   = threadIdx.x;
  const int b   = blockIdx.x >> 6;
  const int hw0 = (blockIdx.x & 63) * 64;

  #pragma unroll
  for (int pass = 0; pass < 4; ++pass) {
    const int row = pass * 16 + (t >> 4);
    const int v4  = (t & 15) * 4;
    f32x4 acc = (f32x4){0.f, 0.f, 0.f, 0.f};
    #pragma unroll
    for (int ks = 0; ks < KS; ++ks)
      acc += *(const f32x4*)&onum[((size_t)(ks * NB + b) * HWN + hw0 + row) * CV + v4];
    *(f32x4*)&tile[row][v4] = acc;
  }
  if (t < 64) {
    float d = 0.f;
    #pragma unroll
    for (int ks = 0; ks < KS; ++ks)
      d += odenom[(size_t)(ks * NB + b) * HWN + hw0 + t];
    dinv[t] = 1.f / fmaxf(d, 1e-30f);
  }
  if (t >= 64 && t < 128) ml[t - 64] = maskadd[b * CV + (t - 64)];
  __syncthreads();

  #pragma unroll
  for (int pass = 0; pass < 4; ++pass) {
    const int v   = pass * 16 + (t >> 4);
    const int hw4 = (t & 15) * 4;
    f32x4 o;
    #pragma unroll
    for (int j = 0; j < 4; ++j)
      o[j] = tile[hw4 + j][v] * dinv[hw4 + j] + ml[v];
    *(f32x4*)&out[((size_t)(b * CV + v)) * HWN + hw0 + hw4] = o;
  }
}

// ---------------------------------------------------------------------------
// Round-6 attention (fallback, small ws)
// ---------------------------------------------------------------------------
struct __align__(16) SmemF {
  union {
    float qs[TM * QS_STR];
    unsigned short p[NW][2][16 * P_STR];
    struct {
      float obuf[NW][TM][CV];
      float lbuf[NW][TM];
    } epi;
  };
};

__global__ __launch_bounds__(512) void attn_fast(
    const _Float16* __restrict__ kT, const unsigned short* __restrict__ vbf,
    const float* __restrict__ query, const float* __restrict__ maskadd,
    float* __restrict__ out)
{
  __shared__ SmemF sm;
  const int t    = threadIdx.x;
  const int w    = t >> 6;
  const int lane = t & 63;
  const int quad = lane >> 4;
  const int l15  = lane & 15;
  const int bidx = blockIdx.x;
  const int b    = bidx & 1;
  const int n0   = ((bidx >> 1) & 127) * TM;

  if (t < 256) {
    const int qc   = t >> 2;
    const int noff = (t & 3) * 8;
    const int slot = qc ^ ((t & 3) << 2);
    const float* qp = query + (size_t)(b * CK + qc) * HWN + n0 + noff;
    f32x4 q0 = *(const f32x4*)(qp);
    f32x4 q1 = *(const f32x4*)(qp + 4);
    #pragma unroll
    for (int j = 0; j < 4; ++j) {
      sm.qs[(noff + j)     * QS_STR + slot] = q0[j];
      sm.qs[(noff + 4 + j) * QS_STR + slot] = q1[j];
    }
  }
  __syncthreads();
  f16x8 qf[2][2];
  #pragma unroll
  for (int f = 0; f < 2; ++f) {
    const int n  = f * 16 + l15;
    const int sw = ((n >> 3) & 7) << 2;
    const float* base = &sm.qs[n * QS_STR];
    #pragma unroll
    for (int h = 0; h < 2; ++h) {
      const int c0 = (h * 32 + quad * 8) ^ sw;
      f32x4 a  = *(const f32x4*)(base + c0);
      f32x4 bb = *(const f32x4*)(base + (c0 ^ 4));
      f16x8 q;
      #pragma unroll
      for (int j = 0; j < 4; ++j) { q[j] = (_Float16)a[j]; q[4 + j] = (_Float16)bb[j]; }
      qf[f][h] = q;
    }
  }
  __syncthreads();

  f32x4 Of[2][4];
  f32x4 Ol[2];
  #pragma unroll
  for (int f = 0; f < 2; ++f) {
    #pragma unroll
    for (int cf = 0; cf < 4; ++cf) Of[f][cf] = (f32x4){0.f, 0.f, 0.f, 0.f};
    Ol[f] = (f32x4){0.f, 0.f, 0.f, 0.f};
  }
  bf16x8 vones;
  #pragma unroll
  for (int i = 0; i < 8; ++i)
    vones[i] = __builtin_bit_cast(__bf16, (unsigned short)0x3F80);

  const _Float16* kbase = kT + (size_t)b * SHW * CK;

  for (int it = 0; it < SHW / 256; ++it) {
    const int key0 = it * 256 + w * 32;
    f16x8 kf[2][2];
    #pragma unroll
    for (int g = 0; g < 2; ++g)
      #pragma unroll
      for (int h = 0; h < 2; ++h)
        kf[g][h] = *(const f16x8*)(kbase +
            (size_t)(key0 + g * 16 + l15) * CK + h * 32 + quad * 8);

    const int s   = it >> 4;
    const int hwv = (it & 15) * 256 + w * 32 + quad * 8;
    bf16x8 vf[4];
    #pragma unroll
    for (int cf = 0; cf < 4; ++cf)
      vf[cf] = ld_bf8_lds(vbf +
          ((size_t)((s * NB + b) * CV + cf * 16 + l15)) * HWN + hwv);

    f32x4 sfv[2][2];
    #pragma unroll
    for (int f = 0; f < 2; ++f)
      #pragma unroll
      for (int g = 0; g < 2; ++g) {
        f32x4 acc = (f32x4){0.f, 0.f, 0.f, 0.f};
        acc = __builtin_amdgcn_mfma_f32_16x16x32_f16(qf[f][0], kf[g][0], acc, 0, 0, 0);
        acc = __builtin_amdgcn_mfma_f32_16x16x32_f16(qf[f][1], kf[g][1], acc, 0, 0, 0);
        sfv[f][g] = acc;
      }

    #pragma unroll
    for (int f = 0; f < 2; ++f)
      #pragma unroll
      for (int g = 0; g < 2; ++g)
        #pragma unroll
        for (int r = 0; r < 4; ++r)
          sfv[f][g][r] = __expf(sfv[f][g][r] - SBIAS);

    #pragma unroll
    for (int f = 0; f < 2; ++f)
      #pragma unroll
      for (int g = 0; g < 2; ++g)
        #pragma unroll
        for (int r = 0; r < 4; ++r)
          sm.p[w][f][(quad * 4 + r) * P_STR + g * 16 + l15] = f2bfu(sfv[f][g][r]);
    asm volatile("s_waitcnt lgkmcnt(0)" ::: "memory");
    bf16x8 pf[2];
    #pragma unroll
    for (int f = 0; f < 2; ++f)
      pf[f] = ld_bf8_lds(&sm.p[w][f][l15 * P_STR + quad * 8]);

    #pragma unroll
    for (int f = 0; f < 2; ++f) {
      #pragma unroll
      for (int cf = 0; cf < 4; ++cf)
        Of[f][cf] = __builtin_amdgcn_mfma_f32_16x16x32_bf16(pf[f], vf[cf], Of[f][cf], 0, 0, 0);
      Ol[f] = __builtin_amdgcn_mfma_f32_16x16x32_bf16(pf[f], vones, Ol[f], 0, 0, 0);
    }
  }

  __syncthreads();
  #pragma unroll
  for (int f = 0; f < 2; ++f)
    #pragma unroll
    for (int r = 0; r < 4; ++r) {
      const int row = f * 16 + quad * 4 + r;
      if (l15 == 0) sm.epi.lbuf[w][row] = Ol[f][r];
      #pragma unroll
      for (int cf = 0; cf < 4; ++cf)
        sm.epi.obuf[w][row][cf * 16 + l15] = Of[f][cf][r];
    }
  __syncthreads();
  {
    const int n   = t & 31;
    const int vhi = t >> 5;
    float denom = 0.f;
    #pragma unroll
    for (int ww = 0; ww < NW; ++ww) denom += sm.epi.lbuf[ww][n];
    const float inv = 1.f / fmaxf(denom, 1e-30f);
    #pragma unroll
    for (int g = 0; g < 4; ++g) {
      const int v = vhi + 16 * g;
      float num = 0.f;
      #pragma unroll
      for (int ww = 0; ww < NW; ++ww) num += sm.epi.obuf[ww][n][v];
      out[((size_t)(b * CV + v)) * HWN + n0 + n] = num * inv + maskadd[b * CV + v];
    }
  }
}

// ---------------------------------------------------------------------------
extern "C" void kernel_launch(void* const* d_in, const int* in_sizes, int n_in,
                              void* d_out, int out_size, void* d_ws, size_t ws_size,
                              hipStream_t stream) {
  const float* keys  = (const float*)d_in[0];
  const float* vals  = (const float*)d_in[1];
  const float* query = (const float*)d_in[2];
  const float* disp  = (const float*)d_in[3];
  const int*   seq   = (const int*)d_in[4];
  float*       out   = (float*)d_out;

  _Float16*       kT   = (_Float16*)d_ws;
  unsigned short* vbf  = (unsigned short*)((char*)d_ws + KT_BYTES);
  float*          mask = (float*)((char*)d_ws + MASK_OFF);

  hipMemsetAsync(mask, 0, (size_t)NB * CV * 4, stream);
  prep_all<<<256 + NB * NS * CV, 512, 0, stream>>>(keys, vals, disp, seq, kT, vbf, mask);

  if (ws_size >= WS2) {
    float* onum   = (float*)((char*)d_ws + ONUM_OFF);
    float* odenom = (float*)((char*)d_ws + ODEN_OFF);
    attn_v6<<<NB * 64 * KS, 512, 0, stream>>>(kT, vbf, query, onum, odenom);
    finalize_k<<<NB * (HWN / 64), 256, 0, stream>>>(onum, odenom, mask, out);
  } else {
    attn_fast<<<NB * (HWN / TM), 512, 0, stream>>>(kT, vbf, query, mask, out);
  }
}